// Round 1
// baseline (1224.518 us; speedup 1.0000x reference)
//
#include <hip/hip_runtime.h>
#include <math.h>

#define NGRID 40
#define NT    1600
#define T2    3200
#define F     128
#define NB    8
#define EPS   1e-5f

__device__ __constant__ const float kINV39 = 1.0f/39.0f;
constexpr float DXDY  = (1.0f/39.0f)*(1.0f/39.0f);
constexpr float SCALE = DXDY * 0.125f;   // DXDY / sqrt(64)

// ---------------------------------------------------------------- edge MLP
__device__ __forceinline__ float mlp_eval(
    float x0, float x1, float x2, float x3,
    const float* __restrict__ W1, const float* __restrict__ b1,
    const float* __restrict__ W2, const float* __restrict__ b2,
    const float* __restrict__ W3, const float* __restrict__ b3)
{
    float h1[32];
    #pragma unroll
    for (int o = 0; o < 32; ++o) {
        float a = b1[o];
        a = fmaf(W1[0*32+o], x0, a);
        a = fmaf(W1[1*32+o], x1, a);
        a = fmaf(W1[2*32+o], x2, a);
        a = fmaf(W1[3*32+o], x3, a);
        h1[o] = fmaxf(a, 0.01f*a);
    }
    float acc = b3[0];
    #pragma unroll
    for (int oc = 0; oc < 64; oc += 32) {
        float h2[32];
        #pragma unroll
        for (int i = 0; i < 32; ++i) h2[i] = b2[oc+i];
        #pragma unroll 4
        for (int k = 0; k < 32; ++k) {
            float hk = h1[k];
            #pragma unroll
            for (int i = 0; i < 32; ++i)
                h2[i] = fmaf(hk, W2[k*64 + oc + i], h2[i]);
        }
        #pragma unroll
        for (int i = 0; i < 32; ++i) {
            float a = h2[i];
            acc = fmaf(fmaxf(a, 0.01f*a), W3[oc+i], acc);
        }
    }
    return acc;
}

__global__ __launch_bounds__(256) void k_mlp_w2(
    const float* __restrict__ kW1, const float* __restrict__ kb1,
    const float* __restrict__ kW2, const float* __restrict__ kb2,
    const float* __restrict__ kW3, const float* __restrict__ kb3,
    const float* __restrict__ fW1, const float* __restrict__ fb1,
    const float* __restrict__ fW2, const float* __restrict__ fb2,
    const float* __restrict__ fW3, const float* __restrict__ fb3,
    float* __restrict__ W2out)
{
    int e = blockIdx.x * 256 + threadIdx.x;           // 0 .. 2,559,999
    int n = e / NT, m = e % NT;
    float x0 = (float)(n / NGRID) * kINV39;
    float x1 = (float)(n % NGRID) * kINV39;
    float x2 = (float)(m / NGRID) * kINV39;
    float x3 = (float)(m % NGRID) * kINV39;
    float wv = mlp_eval(x0,x1,x2,x3, kW1,kb1,kW2,kb2,kW3,kb3);
    float wf = mlp_eval(x0,x1,x2,x3, fW1,fb1,fW2,fb2,fW3,fb3);
    W2out[(size_t)n*T2 + m]      = wv;
    W2out[(size_t)n*T2 + NT + m] = wf;
}

// ------------------------------------------------- P^T, u, w, c precompute
__global__ __launch_bounds__(256) void k_precompute_P(
    const float* __restrict__ Wq, const float* __restrict__ bq,
    const float* __restrict__ Wk, const float* __restrict__ bk,
    float* __restrict__ PT, float* __restrict__ uB,
    float* __restrict__ wB, float* __restrict__ cB)
{
    int j = blockIdx.x;          // layer
    int part = blockIdx.y;       // 0..7: PT tiles, 8: u/w/c
    const float* wq = Wq + (size_t)j*8*F*64;
    const float* wk = Wk + (size_t)j*8*F*64;
    int tid = threadIdx.x;
    if (part == 8) {
        const float* bqj = bq + j*512;
        const float* bkj = bk + j*512;
        if (tid < 128) {
            int k = tid; float a = 0.f;
            for (int h = 0; h < 8; ++h)
                for (int d = 0; d < 64; ++d)
                    a = fmaf(wq[((size_t)h*F + k)*64 + d], bkj[h*64 + d], a);
            uB[j*128 + k] = a;
        } else {
            int k = tid - 128; float a = 0.f;
            for (int h = 0; h < 8; ++h)
                for (int d = 0; d < 64; ++d)
                    a = fmaf(wk[((size_t)h*F + k)*64 + d], bqj[h*64 + d], a);
            wB[j*128 + k] = a;
        }
        if (tid == 0) {
            float a = 0.f;
            for (int i = 0; i < 512; ++i) a = fmaf(bqj[i], bkj[i], a);
            cB[j] = a;
        }
        return;
    }
    // PT[j][k'][k] = P_j[k][k'] = sum_{h,d} Wq[j,h,k,d]*Wk[j,h,k',d]
    int kp = part*16 + (tid >> 4);
    int k0 = (tid & 15) * 8;
    float acc[8] = {0,0,0,0,0,0,0,0};
    for (int h = 0; h < 8; ++h) {
        const float* wkrow = wk + ((size_t)h*F + kp)*64;
        for (int d = 0; d < 64; ++d) {
            float bv = wkrow[d];
            #pragma unroll
            for (int i = 0; i < 8; ++i)
                acc[i] = fmaf(wq[((size_t)h*F + k0 + i)*64 + d], bv, acc[i]);
        }
    }
    #pragma unroll
    for (int i = 0; i < 8; ++i)
        PT[(size_t)j*16384 + (size_t)kp*128 + k0 + i] = acc[i];
}

// ----------------------------------------------------------- LayerNorm 0
__global__ __launch_bounds__(256) void k_ln0_part(
    const float* __restrict__ xy, float* __restrict__ part)
{
    int b = blockIdx.x, blk = blockIdx.y;
    const float4* p = (const float4*)xy + (size_t)b*102400 + blk*4096 + threadIdx.x;
    float s = 0.f, q = 0.f;
    #pragma unroll
    for (int i = 0; i < 16; ++i) {
        float4 v = p[i*256];
        s += (v.x + v.y) + (v.z + v.w);
        q += (v.x*v.x + v.y*v.y) + (v.z*v.z + v.w*v.w);
    }
    #pragma unroll
    for (int off = 32; off >= 1; off >>= 1) {
        s += __shfl_xor(s, off);
        q += __shfl_xor(q, off);
    }
    __shared__ float ss[4], qs[4];
    int wid = threadIdx.x >> 6;
    if ((threadIdx.x & 63) == 0) { ss[wid] = s; qs[wid] = q; }
    __syncthreads();
    if (threadIdx.x == 0) {
        part[((size_t)b*25 + blk)*2 + 0] = ss[0]+ss[1]+ss[2]+ss[3];
        part[((size_t)b*25 + blk)*2 + 1] = qs[0]+qs[1]+qs[2]+qs[3];
    }
}

__global__ void k_ln0_stats(const float* __restrict__ part, float* __restrict__ stats)
{
    int b = threadIdx.x;
    if (b < NB) {
        float s = 0.f, q = 0.f;
        for (int i = 0; i < 25; ++i) {
            s += part[((size_t)b*25 + i)*2 + 0];
            q += part[((size_t)b*25 + i)*2 + 1];
        }
        float mu  = s * (1.0f/409600.0f);
        float var = q * (1.0f/409600.0f) - mu*mu;
        stats[b*2 + 0] = mu;
        stats[b*2 + 1] = rsqrtf(var + EPS);
    }
}

__global__ __launch_bounds__(256) void k_ln0_apply(
    const float* __restrict__ xy, const float* __restrict__ g0,
    const float* __restrict__ b0, const float* __restrict__ stats,
    float* __restrict__ V)
{
    int b = blockIdx.x;
    float mu = stats[b*2], rs = stats[b*2+1];
    int base = blockIdx.y*1024 + threadIdx.x;
    const float4* xv = (const float4*)xy + (size_t)b*102400;
    const float4* gv = (const float4*)g0;
    const float4* bv = (const float4*)b0;
    float4* Vv = (float4*)V + (size_t)b*102400;
    #pragma unroll
    for (int i = 0; i < 4; ++i) {
        int idx = base + i*256;
        float4 x = xv[idx], g = gv[idx], bb = bv[idx], o;
        o.x = (x.x - mu)*rs*g.x + bb.x;
        o.y = (x.y - mu)*rs*g.y + bb.y;
        o.z = (x.z - mu)*rs*g.z + bb.z;
        o.w = (x.w - mu)*rs*g.w + bb.w;
        Vv[idx] = o;
    }
}

// ------------------------------------------ G = A^T B (split-K) + colsum(B)
__global__ __launch_bounds__(256) void k_gemm_gs(
    const float* __restrict__ A, const float* __restrict__ Bm, int rows_per,
    float* __restrict__ Gpart, float* __restrict__ spart)
{
    int kidx = blockIdx.x, khalf = blockIdx.y, b = blockIdx.z;
    const float* Ab = A  + (size_t)b*T2*F;
    const float* Bb = Bm + (size_t)b*T2*F;
    __shared__ float As[4][64];
    __shared__ float Bs[4][128];
    int tid = threadIdx.x;
    int kl = (tid >> 5) * 8, fl = (tid & 31) * 4;
    float acc[8][4] = {};
    float sacc[4] = {0,0,0,0};
    int t0 = kidx * rows_per;
    for (int t = t0; t < t0 + rows_per; t += 4) {
        As[tid >> 6][tid & 63] = Ab[(size_t)(t + (tid >> 6))*F + khalf*64 + (tid & 63)];
        {
            int e = tid*2, row = e >> 7, col = e & 127;
            *(float2*)&Bs[row][col] = *(const float2*)&Bb[(size_t)(t + row)*F + col];
        }
        __syncthreads();
        #pragma unroll
        for (int rr = 0; rr < 4; ++rr) {
            float a[8], bv[4];
            *(float4*)&a[0] = *(const float4*)&As[rr][kl];
            *(float4*)&a[4] = *(const float4*)&As[rr][kl+4];
            *(float4*)&bv[0] = *(const float4*)&Bs[rr][fl];
            #pragma unroll
            for (int i = 0; i < 8; ++i)
                #pragma unroll
                for (int q = 0; q < 4; ++q)
                    acc[i][q] = fmaf(a[i], bv[q], acc[i][q]);
            sacc[0] += bv[0]; sacc[1] += bv[1]; sacc[2] += bv[2]; sacc[3] += bv[3];
        }
        __syncthreads();
    }
    size_t gbase = ((size_t)b*16 + kidx)*16384;
    #pragma unroll
    for (int i = 0; i < 8; ++i)
        *(float4*)&Gpart[gbase + (size_t)(khalf*64 + kl + i)*128 + fl] = *(float4*)&acc[i][0];
    if (khalf == 0 && tid < 32)
        *(float4*)&spart[((size_t)b*16 + kidx)*128 + fl] = *(float4*)&sacc[0];
}

__global__ __launch_bounds__(256) void k_reduce_gs(
    const float* __restrict__ Gpart, const float* __restrict__ spart,
    float* __restrict__ G, float* __restrict__ s)
{
    int b = blockIdx.x;
    for (int idx = threadIdx.x; idx < 16384; idx += 256) {
        float a = 0.f;
        for (int i = 0; i < 16; ++i) a += Gpart[((size_t)b*16 + i)*16384 + idx];
        G[(size_t)b*16384 + idx] = a;
    }
    if (threadIdx.x < 128) {
        float a = 0.f;
        for (int i = 0; i < 16; ++i) a += spart[((size_t)b*16 + i)*128 + threadIdx.x];
        s[b*128 + threadIdx.x] = a;
    }
}

// ------------------------- M = SCALE*(P@G + u⊗s), r = SCALE*(w@G + c*s)
__global__ __launch_bounds__(256) void k_compute_M(
    const float* __restrict__ G, const float* __restrict__ s,
    const float* __restrict__ PTj, const float* __restrict__ uj,
    const float* __restrict__ wj, const float* __restrict__ cj,
    float* __restrict__ Mout, float* __restrict__ rout)
{
    int b = blockIdx.x, khalf = blockIdx.y;
    __shared__ float Gs[32][128];
    __shared__ float Ps[32][64];
    int tid = threadIdx.x;
    int kll = (tid >> 5) * 8, fl = (tid & 31) * 4;
    float acc[8][4] = {};
    for (int kc = 0; kc < 128; kc += 32) {
        for (int e = tid; e < 4096; e += 256)
            Gs[e >> 7][e & 127] = G[(size_t)b*16384 + (size_t)(kc + (e >> 7))*128 + (e & 127)];
        for (int e = tid; e < 2048; e += 256)
            Ps[e >> 6][e & 63] = PTj[(size_t)(kc + (e >> 6))*128 + khalf*64 + (e & 63)];
        __syncthreads();
        #pragma unroll 4
        for (int rr = 0; rr < 32; ++rr) {
            float a[8], bv[4];
            *(float4*)&a[0] = *(const float4*)&Ps[rr][kll];
            *(float4*)&a[4] = *(const float4*)&Ps[rr][kll+4];
            *(float4*)&bv[0] = *(const float4*)&Gs[rr][fl];
            #pragma unroll
            for (int i = 0; i < 8; ++i)
                #pragma unroll
                for (int q = 0; q < 4; ++q)
                    acc[i][q] = fmaf(a[i], bv[q], acc[i][q]);
        }
        __syncthreads();
    }
    int kabs = khalf*64 + kll;
    float sv[4];
    *(float4*)&sv[0] = *(const float4*)&s[b*128 + fl];
    #pragma unroll
    for (int i = 0; i < 8; ++i) {
        float uv = uj[kabs + i];
        float4 o;
        o.x = SCALE*(acc[i][0] + uv*sv[0]);
        o.y = SCALE*(acc[i][1] + uv*sv[1]);
        o.z = SCALE*(acc[i][2] + uv*sv[2]);
        o.w = SCALE*(acc[i][3] + uv*sv[3]);
        *(float4*)&Mout[(size_t)b*16384 + (size_t)(kabs + i)*128 + fl] = o;
    }
    if (khalf == 0 && tid < 128) {
        float rr2 = cj[0] * s[b*128 + tid];
        for (int kp = 0; kp < 128; ++kp)
            rr2 = fmaf(wj[kp], G[(size_t)b*16384 + (size_t)kp*128 + tid], rr2);
        rout[b*128 + tid] = SCALE * rr2;
    }
}

// ----------------------- mid = V@M + r ; optional LN*gl+bl+V, in-place V
__global__ __launch_bounds__(256) void k_mid_ln(
    float* __restrict__ V, const float* __restrict__ M, const float* __restrict__ r,
    const float* __restrict__ glj, const float* __restrict__ blj, int doLN)
{
    int b = blockIdx.x, t0 = blockIdx.y * 64;
    float* Vb = V + (size_t)b*T2*F;
    __shared__ float Ms[32][128];
    __shared__ float Vs[64][36];
    int tid = threadIdx.x;
    int r0 = (tid >> 4) * 4, f0 = (tid & 15) * 8;
    float acc[4][8];
    {
        float rv[8];
        *(float4*)&rv[0] = *(const float4*)&r[b*128 + f0];
        *(float4*)&rv[4] = *(const float4*)&r[b*128 + f0 + 4];
        #pragma unroll
        for (int rr = 0; rr < 4; ++rr)
            #pragma unroll
            for (int i = 0; i < 8; ++i) acc[rr][i] = rv[i];
    }
    for (int kc = 0; kc < 128; kc += 32) {
        for (int e = tid; e < 4096; e += 256)
            Ms[e >> 7][e & 127] = M[(size_t)b*16384 + (size_t)(kc + (e >> 7))*128 + (e & 127)];
        {
            int row = tid >> 2, col = (tid & 3) * 8;
            float4 v0 = *(const float4*)&Vb[(size_t)(t0 + row)*F + kc + col];
            float4 v1 = *(const float4*)&Vb[(size_t)(t0 + row)*F + kc + col + 4];
            *(float4*)&Vs[row][col]     = v0;
            *(float4*)&Vs[row][col + 4] = v1;
        }
        __syncthreads();
        #pragma unroll
        for (int kk = 0; kk < 32; kk += 4) {
            float vvals[4][4];
            #pragma unroll
            for (int rr = 0; rr < 4; ++rr)
                *(float4*)&vvals[rr][0] = *(const float4*)&Vs[r0 + rr][kk];
            #pragma unroll
            for (int k2 = 0; k2 < 4; ++k2) {
                float mrow[8];
                *(float4*)&mrow[0] = *(const float4*)&Ms[kk + k2][f0];
                *(float4*)&mrow[4] = *(const float4*)&Ms[kk + k2][f0 + 4];
                #pragma unroll
                for (int rr = 0; rr < 4; ++rr)
                    #pragma unroll
                    for (int i = 0; i < 8; ++i)
                        acc[rr][i] = fmaf(vvals[rr][k2], mrow[i], acc[rr][i]);
            }
        }
        __syncthreads();
    }
    #pragma unroll
    for (int rr = 0; rr < 4; ++rr) {
        int t = t0 + r0 + rr;
        float outv[8];
        if (doLN) {
            float vo[8];
            *(float4*)&vo[0] = *(const float4*)&Vb[(size_t)t*F + f0];
            *(float4*)&vo[4] = *(const float4*)&Vb[(size_t)t*F + f0 + 4];
            float sm = 0.f;
            #pragma unroll
            for (int i = 0; i < 8; ++i) sm += acc[rr][i];
            sm += __shfl_xor(sm, 1); sm += __shfl_xor(sm, 2);
            sm += __shfl_xor(sm, 4); sm += __shfl_xor(sm, 8);
            float mu = sm * (1.0f/128.0f);
            float dv = 0.f;
            #pragma unroll
            for (int i = 0; i < 8; ++i) { float d = acc[rr][i] - mu; dv = fmaf(d, d, dv); }
            dv += __shfl_xor(dv, 1); dv += __shfl_xor(dv, 2);
            dv += __shfl_xor(dv, 4); dv += __shfl_xor(dv, 8);
            float rs = rsqrtf(dv * (1.0f/128.0f) + EPS);
            #pragma unroll
            for (int i = 0; i < 8; ++i)
                outv[i] = (acc[rr][i] - mu)*rs*glj[f0 + i] + blj[f0 + i] + vo[i];
        } else {
            #pragma unroll
            for (int i = 0; i < 8; ++i) outv[i] = acc[rr][i];
        }
        *(float4*)&Vb[(size_t)t*F + f0]     = *(float4*)&outv[0];
        *(float4*)&Vb[(size_t)t*F + f0 + 4] = *(float4*)&outv[4];
    }
}

// ----------------------------------------- out = DXDY * W2 @ U  (split-K 2)
__global__ __launch_bounds__(128) void k_gemm_out(
    const float* __restrict__ W2m, const float* __restrict__ U, float* __restrict__ opart)
{
    int b = blockIdx.x, nt = blockIdx.y, kh = blockIdx.z;
    int n0 = nt*64, k0 = kh*1600;
    const float* Ub = U + (size_t)b*T2*F;
    __shared__ float Ws[8][68];
    __shared__ float Us[8][128];
    int tid = threadIdx.x;
    int nl = (tid >> 4) * 8, f0 = (tid & 15) * 8;
    float acc[8][8] = {};
    for (int t = k0; t < k0 + 1600; t += 8) {
        {
            int r = tid >> 1, kk = (tid & 1) * 4;
            float4 v = *(const float4*)&W2m[(size_t)(n0 + r)*T2 + t + kk];
            Ws[kk+0][r] = v.x; Ws[kk+1][r] = v.y; Ws[kk+2][r] = v.z; Ws[kk+3][r] = v.w;
        }
        {
            int rr = tid >> 4, col = (tid & 15) * 8;
            float4 v0 = *(const float4*)&Ub[(size_t)(t + rr)*F + col];
            float4 v1 = *(const float4*)&Ub[(size_t)(t + rr)*F + col + 4];
            *(float4*)&Us[rr][col]     = v0;
            *(float4*)&Us[rr][col + 4] = v1;
        }
        __syncthreads();
        #pragma unroll
        for (int kk = 0; kk < 8; ++kk) {
            float a[8], bv[8];
            *(float4*)&a[0] = *(const float4*)&Ws[kk][nl];
            *(float4*)&a[4] = *(const float4*)&Ws[kk][nl+4];
            *(float4*)&bv[0] = *(const float4*)&Us[kk][f0];
            *(float4*)&bv[4] = *(const float4*)&Us[kk][f0+4];
            #pragma unroll
            for (int i = 0; i < 8; ++i)
                #pragma unroll
                for (int q = 0; q < 8; ++q)
                    acc[i][q] = fmaf(a[i], bv[q], acc[i][q]);
        }
        __syncthreads();
    }
    #pragma unroll
    for (int i = 0; i < 8; ++i) {
        size_t base = (size_t)kh*1638400 + ((size_t)b*1600 + n0 + nl + i)*128 + f0;
        float4 o0 = {acc[i][0], acc[i][1], acc[i][2], acc[i][3]};
        float4 o1 = {acc[i][4], acc[i][5], acc[i][6], acc[i][7]};
        *(float4*)&opart[base]     = o0;
        *(float4*)&opart[base + 4] = o1;
    }
}

__global__ __launch_bounds__(256) void k_reduce_out(
    const float* __restrict__ opart, float* __restrict__ out)
{
    size_t e = (size_t)blockIdx.x*256 + threadIdx.x;
    out[e] = DXDY * (opart[e] + opart[e + 1638400]);
}

// --------------------------------------------------------------- launcher
extern "C" void kernel_launch(void* const* d_in, const int* in_sizes, int n_in,
                              void* d_out, int out_size, void* d_ws, size_t ws_size,
                              hipStream_t stream)
{
    const float* xy  = (const float*)d_in[0];
    const float* kW1 = (const float*)d_in[1];
    const float* kb1 = (const float*)d_in[2];
    const float* kW2 = (const float*)d_in[3];
    const float* kb2 = (const float*)d_in[4];
    const float* kW3 = (const float*)d_in[5];
    const float* kb3 = (const float*)d_in[6];
    const float* fW1 = (const float*)d_in[7];
    const float* fb1 = (const float*)d_in[8];
    const float* fW2 = (const float*)d_in[9];
    const float* fb2 = (const float*)d_in[10];
    const float* fW3 = (const float*)d_in[11];
    const float* fb3 = (const float*)d_in[12];
    const float* Wq  = (const float*)d_in[13];
    const float* bq  = (const float*)d_in[14];
    const float* Wk  = (const float*)d_in[15];
    const float* bk  = (const float*)d_in[16];
    const float* g0  = (const float*)d_in[17];
    const float* b0  = (const float*)d_in[18];
    const float* gl  = (const float*)d_in[19];
    const float* bl  = (const float*)d_in[20];
    float* out = (float*)d_out;

    float* ws      = (float*)d_ws;
    float* W2w     = ws;                        // 5,120,000
    float* V       = W2w + 5120000;             // 3,276,800
    float* PT      = V + 3276800;               // 65,536
    float* uB      = PT + 65536;                // 512
    float* wB      = uB + 512;                  // 512
    float* cB      = wB + 512;                  // 4
    float* lnpart  = cB + 4;                    // 400
    float* lnstats = lnpart + 400;              // 16
    float* Gpart   = lnstats + 16;              // 2,097,152
    float* spart   = Gpart + 2097152;           // 16,384
    float* Gm      = spart + 16384;             // 131,072
    float* sm      = Gm + 131072;               // 1,024
    float* Mm      = sm + 1024;                 // 131,072
    float* rm      = Mm + 131072;               // 1,024
    float* opart   = rm + 1024;                 // 3,276,800

    k_mlp_w2<<<dim3(10000), 256, 0, stream>>>(kW1,kb1,kW2,kb2,kW3,kb3,
                                              fW1,fb1,fW2,fb2,fW3,fb3, W2w);
    k_precompute_P<<<dim3(4,9), 256, 0, stream>>>(Wq, bq, Wk, bk, PT, uB, wB, cB);
    k_ln0_part<<<dim3(8,25), 256, 0, stream>>>(xy, lnpart);
    k_ln0_stats<<<1, 64, 0, stream>>>(lnpart, lnstats);
    k_ln0_apply<<<dim3(8,100), 256, 0, stream>>>(xy, g0, b0, lnstats, V);

    for (int j = 0; j < 4; ++j) {
        int rows_per = (j < 3) ? 200 : 100;     // 3200 or 1600 rows over 16 splits
        const float* Bmat = (j < 3) ? V : xy;
        k_gemm_gs<<<dim3(16,2,8), 256, 0, stream>>>(V, Bmat, rows_per, Gpart, spart);
        k_reduce_gs<<<dim3(8), 256, 0, stream>>>(Gpart, spart, Gm, sm);
        k_compute_M<<<dim3(8,2), 256, 0, stream>>>(Gm, sm, PT + (size_t)j*16384,
                                                   uB + j*128, wB + j*128, cB + j, Mm, rm);
        if (j < 3)
            k_mid_ln<<<dim3(8,50), 256, 0, stream>>>(V, Mm, rm, gl + j*128, bl + j*128, 1);
        else
            k_mid_ln<<<dim3(8,50), 256, 0, stream>>>(V, Mm, rm, gl, bl, 0);
    }

    k_gemm_out<<<dim3(8,25,2), 128, 0, stream>>>(W2w, V, opart);
    k_reduce_out<<<dim3(6400), 256, 0, stream>>>(opart, out);
}

// Round 2
// 917.616 us; speedup vs baseline: 1.3345x; 1.3345x over previous
//
#include <hip/hip_runtime.h>
#include <math.h>

#define NGRID 40
#define NT    1600
#define T2    3200
#define F     128
#define NB    8
#define EPS   1e-5f

__device__ __constant__ const float kINV39 = 1.0f/39.0f;
constexpr float DXDY  = (1.0f/39.0f)*(1.0f/39.0f);
constexpr float SCALE = DXDY * 0.125f;   // DXDY / sqrt(64)

typedef __attribute__((ext_vector_type(8))) short bf16x8;
typedef __attribute__((ext_vector_type(4))) float f32x4;

__device__ __forceinline__ unsigned short f2bf(float f) {
    unsigned u = __builtin_bit_cast(unsigned, f);
    unsigned r = u + 0x7FFFu + ((u >> 16) & 1u);
    return (unsigned short)(r >> 16);
}
__device__ __forceinline__ float bf2f(unsigned short h) {
    unsigned u = ((unsigned)h) << 16;
    return __builtin_bit_cast(float, u);
}

// ---------------- precompute W2-layer A-fragments (hi/lo bf16 split) -------
__global__ __launch_bounds__(512) void k_prep_frag(
    const float* __restrict__ kW2, const float* __restrict__ fW2,
    short* __restrict__ Ah, short* __restrict__ Al)
{
    int tid = threadIdx.x;
    int wid = tid >> 6, lane = tid & 63;
    int mlp = wid >> 2, oc = wid & 3;
    const float* W2 = mlp ? fW2 : kW2;
    int row = lane & 15;            // output index within 16-chunk
    int k0 = (lane >> 4) * 8;       // k range
    #pragma unroll
    for (int i = 0; i < 8; ++i) {
        float w = W2[(size_t)(k0 + i) * 64 + oc * 16 + row];
        unsigned short h = f2bf(w);
        Ah[((mlp*4 + oc)*64 + lane)*8 + i] = (short)h;
        Al[((mlp*4 + oc)*64 + lane)*8 + i] = (short)f2bf(w - bf2f(h));
    }
}

// ---------------- MFMA edge-MLP: one wave handles 16 edges, both MLPs -----
__device__ __forceinline__ float mlp_mfma_one(
    int kg, int lane, float x0, float x1, float x2, float x3,
    const float* __restrict__ W1, const float* __restrict__ b1,
    const float* __restrict__ b2, const float* __restrict__ W3,
    const short* __restrict__ Ah, const short* __restrict__ Al, int mlp)
{
    int k0 = kg * 8;
    float h1[8];
    {
        float wa[8], wb[8], wc[8], wd[8], bb[8];
        *(float4*)&wa[0] = *(const float4*)&W1[0*32 + k0];
        *(float4*)&wa[4] = *(const float4*)&W1[0*32 + k0 + 4];
        *(float4*)&wb[0] = *(const float4*)&W1[1*32 + k0];
        *(float4*)&wb[4] = *(const float4*)&W1[1*32 + k0 + 4];
        *(float4*)&wc[0] = *(const float4*)&W1[2*32 + k0];
        *(float4*)&wc[4] = *(const float4*)&W1[2*32 + k0 + 4];
        *(float4*)&wd[0] = *(const float4*)&W1[3*32 + k0];
        *(float4*)&wd[4] = *(const float4*)&W1[3*32 + k0 + 4];
        *(float4*)&bb[0] = *(const float4*)&b1[k0];
        *(float4*)&bb[4] = *(const float4*)&b1[k0 + 4];
        #pragma unroll
        for (int i = 0; i < 8; ++i) {
            float a = bb[i];
            a = fmaf(wa[i], x0, a);
            a = fmaf(wb[i], x1, a);
            a = fmaf(wc[i], x2, a);
            a = fmaf(wd[i], x3, a);
            h1[i] = fmaxf(a, 0.01f*a);
        }
    }
    bf16x8 bh, bl;
    #pragma unroll
    for (int i = 0; i < 8; ++i) {
        unsigned short h = f2bf(h1[i]);
        bh[i] = (short)h;
        bl[i] = (short)f2bf(h1[i] - bf2f(h));
    }
    float acc3 = 0.f;
    #pragma unroll
    for (int oc = 0; oc < 4; ++oc) {
        bf16x8 ah = *(const bf16x8*)&Ah[((mlp*4 + oc)*64 + lane)*8];
        bf16x8 av = *(const bf16x8*)&Al[((mlp*4 + oc)*64 + lane)*8];
        float4 b2v = *(const float4*)&b2[oc*16 + kg*4];
        f32x4 d = {b2v.x, b2v.y, b2v.z, b2v.w};
        d = __builtin_amdgcn_mfma_f32_16x16x32_bf16(ah, bh, d, 0, 0, 0);
        d = __builtin_amdgcn_mfma_f32_16x16x32_bf16(av, bh, d, 0, 0, 0);
        d = __builtin_amdgcn_mfma_f32_16x16x32_bf16(ah, bl, d, 0, 0, 0);
        float4 w3v = *(const float4*)&W3[oc*16 + kg*4];
        float wv[4] = {w3v.x, w3v.y, w3v.z, w3v.w};
        #pragma unroll
        for (int r = 0; r < 4; ++r) {
            float h2 = d[r];
            acc3 = fmaf(fmaxf(h2, 0.01f*h2), wv[r], acc3);
        }
    }
    return acc3;
}

__global__ __launch_bounds__(256) void k_mlp_mfma(
    const float* __restrict__ kW1, const float* __restrict__ kb1,
    const float* __restrict__ kb2, const float* __restrict__ kW3,
    const float* __restrict__ kb3,
    const float* __restrict__ fW1, const float* __restrict__ fb1,
    const float* __restrict__ fb2, const float* __restrict__ fW3,
    const float* __restrict__ fb3,
    const short* __restrict__ Ah, const short* __restrict__ Al,
    float* __restrict__ W2out)
{
    int tid = threadIdx.x;
    int wid = tid >> 6, lane = tid & 63;
    int c = lane & 15, kg = lane >> 4;
    int eb = (blockIdx.x * 4 + wid) * 16;
    int e = eb + c;
    int n = e / NT;
    int m = e - n * NT;
    float x0 = (float)(n / NGRID) * kINV39;
    float x1 = (float)(n % NGRID) * kINV39;
    float x2 = (float)(m / NGRID) * kINV39;
    float x3 = (float)(m % NGRID) * kINV39;
    float r0 = mlp_mfma_one(kg, lane, x0, x1, x2, x3, kW1, kb1, kb2, kW3, Ah, Al, 0);
    float r1 = mlp_mfma_one(kg, lane, x0, x1, x2, x3, fW1, fb1, fb2, fW3, Ah, Al, 1);
    r0 += __shfl_xor(r0, 16); r0 += __shfl_xor(r0, 32);
    r1 += __shfl_xor(r1, 16); r1 += __shfl_xor(r1, 32);
    if (lane < 16) {
        W2out[(size_t)n*T2 + m]      = r0 + kb3[0];
        W2out[(size_t)n*T2 + NT + m] = r1 + fb3[0];
    }
}

// ------------------------------------------------- P^T, u, w, c precompute
__global__ __launch_bounds__(256) void k_precompute_P(
    const float* __restrict__ Wq, const float* __restrict__ bq,
    const float* __restrict__ Wk, const float* __restrict__ bk,
    float* __restrict__ PT, float* __restrict__ uB,
    float* __restrict__ wB, float* __restrict__ cB)
{
    int j = blockIdx.x;          // layer
    int part = blockIdx.y;       // 0..7: PT tiles, 8: u/w/c
    const float* wq = Wq + (size_t)j*8*F*64;
    const float* wk = Wk + (size_t)j*8*F*64;
    int tid = threadIdx.x;
    if (part == 8) {
        const float* bqj = bq + j*512;
        const float* bkj = bk + j*512;
        if (tid < 128) {
            int k = tid; float a = 0.f;
            for (int h = 0; h < 8; ++h)
                for (int d = 0; d < 64; ++d)
                    a = fmaf(wq[((size_t)h*F + k)*64 + d], bkj[h*64 + d], a);
            uB[j*128 + k] = a;
        } else {
            int k = tid - 128; float a = 0.f;
            for (int h = 0; h < 8; ++h)
                for (int d = 0; d < 64; ++d)
                    a = fmaf(wk[((size_t)h*F + k)*64 + d], bqj[h*64 + d], a);
            wB[j*128 + k] = a;
        }
        if (tid == 0) {
            float a = 0.f;
            for (int i = 0; i < 512; ++i) a = fmaf(bqj[i], bkj[i], a);
            cB[j] = a;
        }
        return;
    }
    int kp = part*16 + (tid >> 4);
    int k0 = (tid & 15) * 8;
    float acc[8] = {0,0,0,0,0,0,0,0};
    for (int h = 0; h < 8; ++h) {
        const float* wkrow = wk + ((size_t)h*F + kp)*64;
        for (int d = 0; d < 64; ++d) {
            float bv = wkrow[d];
            #pragma unroll
            for (int i = 0; i < 8; ++i)
                acc[i] = fmaf(wq[((size_t)h*F + k0 + i)*64 + d], bv, acc[i]);
        }
    }
    #pragma unroll
    for (int i = 0; i < 8; ++i)
        PT[(size_t)j*16384 + (size_t)kp*128 + k0 + i] = acc[i];
}

// ----------------------------------------------------------- LayerNorm 0
__global__ __launch_bounds__(256) void k_ln0_part(
    const float* __restrict__ xy, float* __restrict__ part)
{
    int b = blockIdx.x, blk = blockIdx.y;
    const float4* p = (const float4*)xy + (size_t)b*102400 + blk*4096 + threadIdx.x;
    float s = 0.f, q = 0.f;
    #pragma unroll
    for (int i = 0; i < 16; ++i) {
        float4 v = p[i*256];
        s += (v.x + v.y) + (v.z + v.w);
        q += (v.x*v.x + v.y*v.y) + (v.z*v.z + v.w*v.w);
    }
    #pragma unroll
    for (int off = 32; off >= 1; off >>= 1) {
        s += __shfl_xor(s, off);
        q += __shfl_xor(q, off);
    }
    __shared__ float ss[4], qs[4];
    int wid = threadIdx.x >> 6;
    if ((threadIdx.x & 63) == 0) { ss[wid] = s; qs[wid] = q; }
    __syncthreads();
    if (threadIdx.x == 0) {
        part[((size_t)b*25 + blk)*2 + 0] = ss[0]+ss[1]+ss[2]+ss[3];
        part[((size_t)b*25 + blk)*2 + 1] = qs[0]+qs[1]+qs[2]+qs[3];
    }
}

__global__ void k_ln0_stats(const float* __restrict__ part, float* __restrict__ stats)
{
    int b = threadIdx.x;
    if (b < NB) {
        float s = 0.f, q = 0.f;
        for (int i = 0; i < 25; ++i) {
            s += part[((size_t)b*25 + i)*2 + 0];
            q += part[((size_t)b*25 + i)*2 + 1];
        }
        float mu  = s * (1.0f/409600.0f);
        float var = q * (1.0f/409600.0f) - mu*mu;
        stats[b*2 + 0] = mu;
        stats[b*2 + 1] = rsqrtf(var + EPS);
    }
}

__global__ __launch_bounds__(256) void k_ln0_apply(
    const float* __restrict__ xy, const float* __restrict__ g0,
    const float* __restrict__ b0, const float* __restrict__ stats,
    float* __restrict__ V)
{
    int b = blockIdx.x;
    float mu = stats[b*2], rs = stats[b*2+1];
    int base = blockIdx.y*1024 + threadIdx.x;
    const float4* xv = (const float4*)xy + (size_t)b*102400;
    const float4* gv = (const float4*)g0;
    const float4* bv = (const float4*)b0;
    float4* Vv = (float4*)V + (size_t)b*102400;
    #pragma unroll
    for (int i = 0; i < 4; ++i) {
        int idx = base + i*256;
        float4 x = xv[idx], g = gv[idx], bb = bv[idx], o;
        o.x = (x.x - mu)*rs*g.x + bb.x;
        o.y = (x.y - mu)*rs*g.y + bb.y;
        o.z = (x.z - mu)*rs*g.z + bb.z;
        o.w = (x.w - mu)*rs*g.w + bb.w;
        Vv[idx] = o;
    }
}

// ------------------------------------------ G = A^T B (split-K) + colsum(B)
__global__ __launch_bounds__(256) void k_gemm_gs(
    const float* __restrict__ A, const float* __restrict__ Bm, int rows_per,
    float* __restrict__ Gpart, float* __restrict__ spart)
{
    int kidx = blockIdx.x, khalf = blockIdx.y, b = blockIdx.z;
    const float* Ab = A  + (size_t)b*T2*F;
    const float* Bb = Bm + (size_t)b*T2*F;
    __shared__ float As[4][64];
    __shared__ float Bs[4][128];
    int tid = threadIdx.x;
    int kl = (tid >> 5) * 8, fl = (tid & 31) * 4;
    float acc[8][4] = {};
    float sacc[4] = {0,0,0,0};
    int t0 = kidx * rows_per;
    for (int t = t0; t < t0 + rows_per; t += 4) {
        As[tid >> 6][tid & 63] = Ab[(size_t)(t + (tid >> 6))*F + khalf*64 + (tid & 63)];
        {
            int e = tid*2, row = e >> 7, col = e & 127;
            *(float2*)&Bs[row][col] = *(const float2*)&Bb[(size_t)(t + row)*F + col];
        }
        __syncthreads();
        #pragma unroll
        for (int rr = 0; rr < 4; ++rr) {
            float a[8], bv[4];
            *(float4*)&a[0] = *(const float4*)&As[rr][kl];
            *(float4*)&a[4] = *(const float4*)&As[rr][kl+4];
            *(float4*)&bv[0] = *(const float4*)&Bs[rr][fl];
            #pragma unroll
            for (int i = 0; i < 8; ++i)
                #pragma unroll
                for (int q = 0; q < 4; ++q)
                    acc[i][q] = fmaf(a[i], bv[q], acc[i][q]);
            sacc[0] += bv[0]; sacc[1] += bv[1]; sacc[2] += bv[2]; sacc[3] += bv[3];
        }
        __syncthreads();
    }
    size_t gbase = ((size_t)b*16 + kidx)*16384;
    #pragma unroll
    for (int i = 0; i < 8; ++i)
        *(float4*)&Gpart[gbase + (size_t)(khalf*64 + kl + i)*128 + fl] = *(float4*)&acc[i][0];
    if (khalf == 0 && tid < 32)
        *(float4*)&spart[((size_t)b*16 + kidx)*128 + fl] = *(float4*)&sacc[0];
}

__global__ __launch_bounds__(256) void k_reduce_gs(
    const float* __restrict__ Gpart, const float* __restrict__ spart,
    float* __restrict__ G, float* __restrict__ s)
{
    int b = blockIdx.x;
    int idx = blockIdx.y * 1024 + threadIdx.x;
    #pragma unroll
    for (int o = 0; o < 1024; o += 256) {
        float a = 0.f;
        #pragma unroll 4
        for (int i = 0; i < 16; ++i) a += Gpart[((size_t)b*16 + i)*16384 + idx + o];
        G[(size_t)b*16384 + idx + o] = a;
    }
    if (blockIdx.y == 0 && threadIdx.x < 128) {
        float a = 0.f;
        for (int i = 0; i < 16; ++i) a += spart[((size_t)b*16 + i)*128 + threadIdx.x];
        s[b*128 + threadIdx.x] = a;
    }
}

// ------------------------- M = SCALE*(P@G + u⊗s), r = SCALE*(w@G + c*s)
__global__ __launch_bounds__(256) void k_compute_M(
    const float* __restrict__ G, const float* __restrict__ s,
    const float* __restrict__ PTj, const float* __restrict__ uj,
    const float* __restrict__ wj, const float* __restrict__ cj,
    float* __restrict__ Mout, float* __restrict__ rout)
{
    int b = blockIdx.x, khalf = blockIdx.y;
    __shared__ float Gs[32][128];
    __shared__ float Ps[32][64];
    int tid = threadIdx.x;
    int kll = (tid >> 5) * 8, fl = (tid & 31) * 4;
    float acc[8][4] = {};
    for (int kc = 0; kc < 128; kc += 32) {
        for (int e = tid; e < 4096; e += 256)
            Gs[e >> 7][e & 127] = G[(size_t)b*16384 + (size_t)(kc + (e >> 7))*128 + (e & 127)];
        for (int e = tid; e < 2048; e += 256)
            Ps[e >> 6][e & 63] = PTj[(size_t)(kc + (e >> 6))*128 + khalf*64 + (e & 63)];
        __syncthreads();
        #pragma unroll 4
        for (int rr = 0; rr < 32; ++rr) {
            float a[8], bv[4];
            *(float4*)&a[0] = *(const float4*)&Ps[rr][kll];
            *(float4*)&a[4] = *(const float4*)&Ps[rr][kll+4];
            *(float4*)&bv[0] = *(const float4*)&Gs[rr][fl];
            #pragma unroll
            for (int i = 0; i < 8; ++i)
                #pragma unroll
                for (int q = 0; q < 4; ++q)
                    acc[i][q] = fmaf(a[i], bv[q], acc[i][q]);
        }
        __syncthreads();
    }
    int kabs = khalf*64 + kll;
    float sv[4];
    *(float4*)&sv[0] = *(const float4*)&s[b*128 + fl];
    #pragma unroll
    for (int i = 0; i < 8; ++i) {
        float uv = uj[kabs + i];
        float4 o;
        o.x = SCALE*(acc[i][0] + uv*sv[0]);
        o.y = SCALE*(acc[i][1] + uv*sv[1]);
        o.z = SCALE*(acc[i][2] + uv*sv[2]);
        o.w = SCALE*(acc[i][3] + uv*sv[3]);
        *(float4*)&Mout[(size_t)b*16384 + (size_t)(kabs + i)*128 + fl] = o;
    }
    if (khalf == 0 && tid < 128) {
        float rr2 = cj[0] * s[b*128 + tid];
        for (int kp = 0; kp < 128; ++kp)
            rr2 = fmaf(wj[kp], G[(size_t)b*16384 + (size_t)kp*128 + tid], rr2);
        rout[b*128 + tid] = SCALE * rr2;
    }
}

// ----------------------- mid = V@M + r ; optional LN*gl+bl+V, in-place V
__global__ __launch_bounds__(256) void k_mid_ln(
    float* __restrict__ V, const float* __restrict__ M, const float* __restrict__ r,
    const float* __restrict__ glj, const float* __restrict__ blj, int doLN)
{
    int b = blockIdx.x, t0 = blockIdx.y * 64;
    float* Vb = V + (size_t)b*T2*F;
    __shared__ float Ms[32][128];
    __shared__ float Vs[64][36];
    int tid = threadIdx.x;
    int r0 = (tid >> 4) * 4, f0 = (tid & 15) * 8;
    float acc[4][8];
    {
        float rv[8];
        *(float4*)&rv[0] = *(const float4*)&r[b*128 + f0];
        *(float4*)&rv[4] = *(const float4*)&r[b*128 + f0 + 4];
        #pragma unroll
        for (int rr = 0; rr < 4; ++rr)
            #pragma unroll
            for (int i = 0; i < 8; ++i) acc[rr][i] = rv[i];
    }
    for (int kc = 0; kc < 128; kc += 32) {
        for (int e = tid; e < 4096; e += 256)
            Ms[e >> 7][e & 127] = M[(size_t)b*16384 + (size_t)(kc + (e >> 7))*128 + (e & 127)];
        {
            int row = tid >> 2, col = (tid & 3) * 8;
            float4 v0 = *(const float4*)&Vb[(size_t)(t0 + row)*F + kc + col];
            float4 v1 = *(const float4*)&Vb[(size_t)(t0 + row)*F + kc + col + 4];
            *(float4*)&Vs[row][col]     = v0;
            *(float4*)&Vs[row][col + 4] = v1;
        }
        __syncthreads();
        #pragma unroll
        for (int kk = 0; kk < 32; kk += 4) {
            float vvals[4][4];
            #pragma unroll
            for (int rr = 0; rr < 4; ++rr)
                *(float4*)&vvals[rr][0] = *(const float4*)&Vs[r0 + rr][kk];
            #pragma unroll
            for (int k2 = 0; k2 < 4; ++k2) {
                float mrow[8];
                *(float4*)&mrow[0] = *(const float4*)&Ms[kk + k2][f0];
                *(float4*)&mrow[4] = *(const float4*)&Ms[kk + k2][f0 + 4];
                #pragma unroll
                for (int rr = 0; rr < 4; ++rr)
                    #pragma unroll
                    for (int i = 0; i < 8; ++i)
                        acc[rr][i] = fmaf(vvals[rr][k2], mrow[i], acc[rr][i]);
            }
        }
        __syncthreads();
    }
    #pragma unroll
    for (int rr = 0; rr < 4; ++rr) {
        int t = t0 + r0 + rr;
        float outv[8];
        if (doLN) {
            float vo[8];
            *(float4*)&vo[0] = *(const float4*)&Vb[(size_t)t*F + f0];
            *(float4*)&vo[4] = *(const float4*)&Vb[(size_t)t*F + f0 + 4];
            float sm = 0.f;
            #pragma unroll
            for (int i = 0; i < 8; ++i) sm += acc[rr][i];
            sm += __shfl_xor(sm, 1); sm += __shfl_xor(sm, 2);
            sm += __shfl_xor(sm, 4); sm += __shfl_xor(sm, 8);
            float mu = sm * (1.0f/128.0f);
            float dv = 0.f;
            #pragma unroll
            for (int i = 0; i < 8; ++i) { float d = acc[rr][i] - mu; dv = fmaf(d, d, dv); }
            dv += __shfl_xor(dv, 1); dv += __shfl_xor(dv, 2);
            dv += __shfl_xor(dv, 4); dv += __shfl_xor(dv, 8);
            float rs = rsqrtf(dv * (1.0f/128.0f) + EPS);
            #pragma unroll
            for (int i = 0; i < 8; ++i)
                outv[i] = (acc[rr][i] - mu)*rs*glj[f0 + i] + blj[f0 + i] + vo[i];
        } else {
            #pragma unroll
            for (int i = 0; i < 8; ++i) outv[i] = acc[rr][i];
        }
        *(float4*)&Vb[(size_t)t*F + f0]     = *(float4*)&outv[0];
        *(float4*)&Vb[(size_t)t*F + f0 + 4] = *(float4*)&outv[4];
    }
}

// ----------------------------------------- out = DXDY * W2 @ U  (split-K 4)
__global__ __launch_bounds__(256) void k_gemm_out(
    const float* __restrict__ W2m, const float* __restrict__ U, float* __restrict__ opart)
{
    int b = blockIdx.x, nt = blockIdx.y, kq = blockIdx.z;
    int n0 = nt*64, k0 = kq*800;
    const float* Ub = U + (size_t)b*T2*F;
    __shared__ float Ws[8][72];
    __shared__ float Us[8][128];
    int tid = threadIdx.x;
    int nl = (tid >> 5) * 8, f0 = (tid & 31) * 4;
    float acc[8][4] = {};
    for (int t = k0; t < k0 + 800; t += 8) {
        if (tid < 128) {
            int r = tid >> 1, kk = (tid & 1) * 4;
            float4 v = *(const float4*)&W2m[(size_t)(n0 + r)*T2 + t + kk];
            Ws[kk+0][r] = v.x; Ws[kk+1][r] = v.y; Ws[kk+2][r] = v.z; Ws[kk+3][r] = v.w;
        }
        {
            int rr = tid >> 5, col = (tid & 31) * 4;
            *(float4*)&Us[rr][col] = *(const float4*)&Ub[(size_t)(t + rr)*F + col];
        }
        __syncthreads();
        #pragma unroll
        for (int kk = 0; kk < 8; ++kk) {
            float a[8], bv[4];
            *(float4*)&a[0] = *(const float4*)&Ws[kk][nl];
            *(float4*)&a[4] = *(const float4*)&Ws[kk][nl+4];
            *(float4*)&bv[0] = *(const float4*)&Us[kk][f0];
            #pragma unroll
            for (int i = 0; i < 8; ++i)
                #pragma unroll
                for (int q = 0; q < 4; ++q)
                    acc[i][q] = fmaf(a[i], bv[q], acc[i][q]);
        }
        __syncthreads();
    }
    #pragma unroll
    for (int i = 0; i < 8; ++i) {
        size_t base = (size_t)kq*1638400 + ((size_t)b*1600 + n0 + nl + i)*128 + f0;
        float4 o = {acc[i][0], acc[i][1], acc[i][2], acc[i][3]};
        *(float4*)&opart[base] = o;
    }
}

__global__ __launch_bounds__(256) void k_reduce_out(
    const float* __restrict__ opart, float* __restrict__ out)
{
    size_t e = (size_t)blockIdx.x*256 + threadIdx.x;
    out[e] = DXDY * ((opart[e] + opart[e + 1638400]) +
                     (opart[e + 2*1638400] + opart[e + 3*1638400]));
}

// --------------------------------------------------------------- launcher
extern "C" void kernel_launch(void* const* d_in, const int* in_sizes, int n_in,
                              void* d_out, int out_size, void* d_ws, size_t ws_size,
                              hipStream_t stream)
{
    const float* xy  = (const float*)d_in[0];
    const float* kW1 = (const float*)d_in[1];
    const float* kb1 = (const float*)d_in[2];
    const float* kW2 = (const float*)d_in[3];
    const float* kb2 = (const float*)d_in[4];
    const float* kW3 = (const float*)d_in[5];
    const float* kb3 = (const float*)d_in[6];
    const float* fW1 = (const float*)d_in[7];
    const float* fb1 = (const float*)d_in[8];
    const float* fW2 = (const float*)d_in[9];
    const float* fb2 = (const float*)d_in[10];
    const float* fW3 = (const float*)d_in[11];
    const float* fb3 = (const float*)d_in[12];
    const float* Wq  = (const float*)d_in[13];
    const float* bq  = (const float*)d_in[14];
    const float* Wk  = (const float*)d_in[15];
    const float* bk  = (const float*)d_in[16];
    const float* g0  = (const float*)d_in[17];
    const float* b0  = (const float*)d_in[18];
    const float* gl  = (const float*)d_in[19];
    const float* bl  = (const float*)d_in[20];
    float* out = (float*)d_out;

    float* ws      = (float*)d_ws;
    float* W2w     = ws;                        // 5,120,000
    float* V       = W2w + 5120000;             // 3,276,800
    float* PT      = V + 3276800;               // 65,536
    float* uB      = PT + 65536;                // 512
    float* wB      = uB + 512;                  // 512
    float* cB      = wB + 512;                  // 4
    float* lnpart  = cB + 4;                    // 400
    float* lnstats = lnpart + 400;              // 16
    float* Gpart   = lnstats + 16;              // 2,097,152
    float* spart   = Gpart + 2097152;           // 16,384
    float* Gm      = spart + 16384;             // 131,072
    float* sm      = Gm + 131072;               // 1,024
    float* Mm      = sm + 1024;                 // 131,072
    float* rm      = Mm + 131072;               // 1,024
    float* opart   = rm + 1024;                 // 6,553,600
    short* AhF     = (short*)(opart + 6553600); // 4096 shorts
    short* AlF     = AhF + 4096;                // 4096 shorts

    k_prep_frag<<<1, 512, 0, stream>>>(kW2, fW2, AhF, AlF);
    k_mlp_mfma<<<dim3(40000), 256, 0, stream>>>(kW1, kb1, kb2, kW3, kb3,
                                                fW1, fb1, fb2, fW3, fb3,
                                                AhF, AlF, W2w);
    k_precompute_P<<<dim3(4,9), 256, 0, stream>>>(Wq, bq, Wk, bk, PT, uB, wB, cB);
    k_ln0_part<<<dim3(8,25), 256, 0, stream>>>(xy, lnpart);
    k_ln0_stats<<<1, 64, 0, stream>>>(lnpart, lnstats);
    k_ln0_apply<<<dim3(8,100), 256, 0, stream>>>(xy, g0, b0, lnstats, V);

    for (int j = 0; j < 4; ++j) {
        int rows_per = (j < 3) ? 200 : 100;
        const float* Bmat = (j < 3) ? V : xy;
        k_gemm_gs<<<dim3(16,2,8), 256, 0, stream>>>(V, Bmat, rows_per, Gpart, spart);
        k_reduce_gs<<<dim3(8,16), 256, 0, stream>>>(Gpart, spart, Gm, sm);
        k_compute_M<<<dim3(8,2), 256, 0, stream>>>(Gm, sm, PT + (size_t)j*16384,
                                                   uB + j*128, wB + j*128, cB + j, Mm, rm);
        if (j < 3)
            k_mid_ln<<<dim3(8,50), 256, 0, stream>>>(V, Mm, rm, gl + j*128, bl + j*128, 1);
        else
            k_mid_ln<<<dim3(8,50), 256, 0, stream>>>(V, Mm, rm, gl, bl, 0);
    }

    k_gemm_out<<<dim3(8,25,4), 256, 0, stream>>>(W2w, V, opart);
    k_reduce_out<<<dim3(6400), 256, 0, stream>>>(opart, out);
}

// Round 3
// 805.599 us; speedup vs baseline: 1.5200x; 1.1390x over previous
//
#include <hip/hip_runtime.h>
#include <math.h>

#define NGRID 40
#define NT    1600
#define T2    3200
#define F     128
#define NB    8
#define EPS   1e-5f

__device__ __constant__ const float kINV39 = 1.0f/39.0f;
constexpr float DXDY  = (1.0f/39.0f)*(1.0f/39.0f);
constexpr float SCALE = DXDY * 0.125f;   // DXDY / sqrt(64)

typedef __attribute__((ext_vector_type(8))) short bf16x8;
typedef __attribute__((ext_vector_type(4))) float f32x4;
typedef __attribute__((ext_vector_type(4))) unsigned uint4v;

__device__ __forceinline__ unsigned short f2bf(float f) {
    unsigned u = __builtin_bit_cast(unsigned, f);
    unsigned r = u + 0x7FFFu + ((u >> 16) & 1u);
    return (unsigned short)(r >> 16);
}
__device__ __forceinline__ float bf2f(unsigned short h) {
    unsigned u = ((unsigned)h) << 16;
    return __builtin_bit_cast(float, u);
}

// ---------------- precompute W2-layer A-fragments (hi/lo bf16 split) -------
__global__ __launch_bounds__(512) void k_prep_frag(
    const float* __restrict__ kW2, const float* __restrict__ fW2,
    short* __restrict__ Ah, short* __restrict__ Al)
{
    int tid = threadIdx.x;
    int wid = tid >> 6, lane = tid & 63;
    int mlp = wid >> 2, oc = wid & 3;
    const float* W2 = mlp ? fW2 : kW2;
    int row = lane & 15;            // output index within 16-chunk
    int k0 = (lane >> 4) * 8;       // k range
    #pragma unroll
    for (int i = 0; i < 8; ++i) {
        float w = W2[(size_t)(k0 + i) * 64 + oc * 16 + row];
        unsigned short h = f2bf(w);
        Ah[((mlp*4 + oc)*64 + lane)*8 + i] = (short)h;
        Al[((mlp*4 + oc)*64 + lane)*8 + i] = (short)f2bf(w - bf2f(h));
    }
}

// ---------------- precompute separable layer-1 tables u,v per node --------
// layout: uk[1600][32] | vk[1600][32] | uf[1600][32] | vf[1600][32]
__global__ __launch_bounds__(256) void k_prep_uv(
    const float* __restrict__ kW1, const float* __restrict__ kb1,
    const float* __restrict__ fW1, const float* __restrict__ fb1,
    float* __restrict__ uv)
{
    int idx = blockIdx.x * 256 + threadIdx.x;    // 0..51199
    int node = idx >> 5, o = idx & 31;
    float x0 = (float)(node / NGRID) * kINV39;
    float x1 = (float)(node % NGRID) * kINV39;
    uv[idx]          = fmaf(kW1[o], x0, fmaf(kW1[32+o], x1, kb1[o]));
    uv[51200 + idx]  = fmaf(kW1[64+o], x0, kW1[96+o]*x1);
    uv[102400 + idx] = fmaf(fW1[o], x0, fmaf(fW1[32+o], x1, fb1[o]));
    uv[153600 + idx] = fmaf(fW1[64+o], x0, fW1[96+o]*x1);
}

// ---------------- MFMA edge-MLP: grid-stride, persistent frags in VGPR ----
__global__ __launch_bounds__(256, 2) void k_mlp_mfma(
    const float* __restrict__ uv,
    const float* __restrict__ kb2, const float* __restrict__ kW3,
    const float* __restrict__ kb3,
    const float* __restrict__ fb2, const float* __restrict__ fW3,
    const float* __restrict__ fb3,
    const short* __restrict__ Ah, const short* __restrict__ Al,
    float* __restrict__ W2out)
{
    int tid = threadIdx.x;
    int wid = tid >> 6, lane = tid & 63;
    int c = lane & 15, kg = lane >> 4;
    int k0 = kg * 8;

    // hoist all fragments into registers once (no per-tile L1 re-read)
    bf16x8 AHf[2][4], ALf[2][4];
    float4 B2f[2][4], W3f[2][4];
    #pragma unroll
    for (int mlp = 0; mlp < 2; ++mlp) {
        const float* b2p = mlp ? fb2 : kb2;
        const float* w3p = mlp ? fW3 : kW3;
        #pragma unroll
        for (int oc = 0; oc < 4; ++oc) {
            AHf[mlp][oc] = *(const bf16x8*)&Ah[((mlp*4 + oc)*64 + lane)*8];
            ALf[mlp][oc] = *(const bf16x8*)&Al[((mlp*4 + oc)*64 + lane)*8];
            B2f[mlp][oc] = *(const float4*)&b2p[oc*16 + kg*4];
            W3f[mlp][oc] = *(const float4*)&w3p[oc*16 + kg*4];
        }
    }
    float bias0 = kb3[0], bias1 = fb3[0];

    for (int tile = blockIdx.x*4 + wid; tile < 160000; tile += 2048) {
        int n = tile / 100;
        int m = (tile - n*100)*16 + c;
        float res0, res1;
        #pragma unroll
        for (int mlp = 0; mlp < 2; ++mlp) {
            const float* up = uv + mlp*102400 + n*32 + k0;
            const float* vp = uv + mlp*102400 + 51200 + m*32 + k0;
            float4 ua = *(const float4*)up;
            float4 ub = *(const float4*)(up + 4);
            float4 va = *(const float4*)vp;
            float4 vb = *(const float4*)(vp + 4);
            float h[8] = {ua.x+va.x, ua.y+va.y, ua.z+va.z, ua.w+va.w,
                          ub.x+vb.x, ub.y+vb.y, ub.z+vb.z, ub.w+vb.w};
            #pragma unroll
            for (int i = 0; i < 8; ++i) h[i] = fmaxf(h[i], 0.01f*h[i]);
            // bf16 hi/lo split via truncation + v_perm pack
            unsigned bhp[4], blp[4];
            #pragma unroll
            for (int p = 0; p < 4; ++p) {
                unsigned u0 = __builtin_bit_cast(unsigned, h[2*p]);
                unsigned u1 = __builtin_bit_cast(unsigned, h[2*p+1]);
                bhp[p] = __builtin_amdgcn_perm(u1, u0, 0x07060302u);
                float t0 = __builtin_bit_cast(float, u0 & 0xffff0000u);
                float t1 = __builtin_bit_cast(float, u1 & 0xffff0000u);
                blp[p] = __builtin_amdgcn_perm(
                    __builtin_bit_cast(unsigned, h[2*p+1] - t1),
                    __builtin_bit_cast(unsigned, h[2*p] - t0), 0x07060302u);
            }
            uint4v bhv = {bhp[0], bhp[1], bhp[2], bhp[3]};
            uint4v blv = {blp[0], blp[1], blp[2], blp[3]};
            bf16x8 bh = __builtin_bit_cast(bf16x8, bhv);
            bf16x8 bl = __builtin_bit_cast(bf16x8, blv);
            float acc = 0.f;
            #pragma unroll
            for (int oc = 0; oc < 4; ++oc) {
                f32x4 d = {B2f[mlp][oc].x, B2f[mlp][oc].y,
                           B2f[mlp][oc].z, B2f[mlp][oc].w};
                d = __builtin_amdgcn_mfma_f32_16x16x32_bf16(AHf[mlp][oc], bh, d, 0, 0, 0);
                d = __builtin_amdgcn_mfma_f32_16x16x32_bf16(ALf[mlp][oc], bh, d, 0, 0, 0);
                d = __builtin_amdgcn_mfma_f32_16x16x32_bf16(AHf[mlp][oc], bl, d, 0, 0, 0);
                float w3v[4] = {W3f[mlp][oc].x, W3f[mlp][oc].y,
                                W3f[mlp][oc].z, W3f[mlp][oc].w};
                #pragma unroll
                for (int r = 0; r < 4; ++r)
                    acc = fmaf(fmaxf(d[r], 0.01f*d[r]), w3v[r], acc);
            }
            if (mlp == 0) res0 = acc; else res1 = acc;
        }
        res0 += __shfl_xor(res0, 16); res0 += __shfl_xor(res0, 32);
        res1 += __shfl_xor(res1, 16); res1 += __shfl_xor(res1, 32);
        if (lane < 16) {
            W2out[(size_t)n*T2 + m]      = res0 + bias0;
            W2out[(size_t)n*T2 + NT + m] = res1 + bias1;
        }
    }
}

// ------------------------------------------------- P^T, u, w, c precompute
__global__ __launch_bounds__(256) void k_precompute_P(
    const float* __restrict__ Wq, const float* __restrict__ bq,
    const float* __restrict__ Wk, const float* __restrict__ bk,
    float* __restrict__ PT, float* __restrict__ uB,
    float* __restrict__ wB, float* __restrict__ cB)
{
    int j = blockIdx.x;          // layer
    int part = blockIdx.y;       // 0..7: PT tiles, 8: u/w/c
    const float* wq = Wq + (size_t)j*8*F*64;
    const float* wk = Wk + (size_t)j*8*F*64;
    int tid = threadIdx.x;
    if (part == 8) {
        const float* bqj = bq + j*512;
        const float* bkj = bk + j*512;
        if (tid < 128) {
            int k = tid; float a = 0.f;
            for (int h = 0; h < 8; ++h)
                for (int d = 0; d < 64; ++d)
                    a = fmaf(wq[((size_t)h*F + k)*64 + d], bkj[h*64 + d], a);
            uB[j*128 + k] = a;
        } else {
            int k = tid - 128; float a = 0.f;
            for (int h = 0; h < 8; ++h)
                for (int d = 0; d < 64; ++d)
                    a = fmaf(wk[((size_t)h*F + k)*64 + d], bqj[h*64 + d], a);
            wB[j*128 + k] = a;
        }
        if (tid == 0) {
            float a = 0.f;
            for (int i = 0; i < 512; ++i) a = fmaf(bqj[i], bkj[i], a);
            cB[j] = a;
        }
        return;
    }
    int kp = part*16 + (tid >> 4);
    int k0 = (tid & 15) * 8;
    float acc[8] = {0,0,0,0,0,0,0,0};
    for (int h = 0; h < 8; ++h) {
        const float* wkrow = wk + ((size_t)h*F + kp)*64;
        for (int d = 0; d < 64; ++d) {
            float bv = wkrow[d];
            #pragma unroll
            for (int i = 0; i < 8; ++i)
                acc[i] = fmaf(wq[((size_t)h*F + k0 + i)*64 + d], bv, acc[i]);
        }
    }
    #pragma unroll
    for (int i = 0; i < 8; ++i)
        PT[(size_t)j*16384 + (size_t)kp*128 + k0 + i] = acc[i];
}

// ----------------------------------------------------------- LayerNorm 0
__global__ __launch_bounds__(256) void k_ln0_part(
    const float* __restrict__ xy, float* __restrict__ part)
{
    int b = blockIdx.x, blk = blockIdx.y;
    const float4* p = (const float4*)xy + (size_t)b*102400 + blk*4096 + threadIdx.x;
    float s = 0.f, q = 0.f;
    #pragma unroll
    for (int i = 0; i < 16; ++i) {
        float4 v = p[i*256];
        s += (v.x + v.y) + (v.z + v.w);
        q += (v.x*v.x + v.y*v.y) + (v.z*v.z + v.w*v.w);
    }
    #pragma unroll
    for (int off = 32; off >= 1; off >>= 1) {
        s += __shfl_xor(s, off);
        q += __shfl_xor(q, off);
    }
    __shared__ float ss[4], qs[4];
    int wid = threadIdx.x >> 6;
    if ((threadIdx.x & 63) == 0) { ss[wid] = s; qs[wid] = q; }
    __syncthreads();
    if (threadIdx.x == 0) {
        part[((size_t)b*25 + blk)*2 + 0] = ss[0]+ss[1]+ss[2]+ss[3];
        part[((size_t)b*25 + blk)*2 + 1] = qs[0]+qs[1]+qs[2]+qs[3];
    }
}

__global__ void k_ln0_stats(const float* __restrict__ part, float* __restrict__ stats)
{
    int b = threadIdx.x;
    if (b < NB) {
        float s = 0.f, q = 0.f;
        for (int i = 0; i < 25; ++i) {
            s += part[((size_t)b*25 + i)*2 + 0];
            q += part[((size_t)b*25 + i)*2 + 1];
        }
        float mu  = s * (1.0f/409600.0f);
        float var = q * (1.0f/409600.0f) - mu*mu;
        stats[b*2 + 0] = mu;
        stats[b*2 + 1] = rsqrtf(var + EPS);
    }
}

__global__ __launch_bounds__(256) void k_ln0_apply(
    const float* __restrict__ xy, const float* __restrict__ g0,
    const float* __restrict__ b0, const float* __restrict__ stats,
    float* __restrict__ V)
{
    int b = blockIdx.x;
    float mu = stats[b*2], rs = stats[b*2+1];
    int base = blockIdx.y*1024 + threadIdx.x;
    const float4* xv = (const float4*)xy + (size_t)b*102400;
    const float4* gv = (const float4*)g0;
    const float4* bv = (const float4*)b0;
    float4* Vv = (float4*)V + (size_t)b*102400;
    #pragma unroll
    for (int i = 0; i < 4; ++i) {
        int idx = base + i*256;
        float4 x = xv[idx], g = gv[idx], bb = bv[idx], o;
        o.x = (x.x - mu)*rs*g.x + bb.x;
        o.y = (x.y - mu)*rs*g.y + bb.y;
        o.z = (x.z - mu)*rs*g.z + bb.z;
        o.w = (x.w - mu)*rs*g.w + bb.w;
        Vv[idx] = o;
    }
}

// ------------------------------------------ G = A^T B (split-K) + colsum(B)
__global__ __launch_bounds__(256) void k_gemm_gs(
    const float* __restrict__ A, const float* __restrict__ Bm, int rows_per,
    float* __restrict__ Gpart, float* __restrict__ spart)
{
    int kidx = blockIdx.x, khalf = blockIdx.y, b = blockIdx.z;
    const float* Ab = A  + (size_t)b*T2*F;
    const float* Bb = Bm + (size_t)b*T2*F;
    __shared__ float As[4][64];
    __shared__ float Bs[4][128];
    int tid = threadIdx.x;
    int kl = (tid >> 5) * 8, fl = (tid & 31) * 4;
    float acc[8][4] = {};
    float sacc[4] = {0,0,0,0};
    int t0 = kidx * rows_per;
    for (int t = t0; t < t0 + rows_per; t += 4) {
        As[tid >> 6][tid & 63] = Ab[(size_t)(t + (tid >> 6))*F + khalf*64 + (tid & 63)];
        {
            int e = tid*2, row = e >> 7, col = e & 127;
            *(float2*)&Bs[row][col] = *(const float2*)&Bb[(size_t)(t + row)*F + col];
        }
        __syncthreads();
        #pragma unroll
        for (int rr = 0; rr < 4; ++rr) {
            float a[8], bv[4];
            *(float4*)&a[0] = *(const float4*)&As[rr][kl];
            *(float4*)&a[4] = *(const float4*)&As[rr][kl+4];
            *(float4*)&bv[0] = *(const float4*)&Bs[rr][fl];
            #pragma unroll
            for (int i = 0; i < 8; ++i)
                #pragma unroll
                for (int q = 0; q < 4; ++q)
                    acc[i][q] = fmaf(a[i], bv[q], acc[i][q]);
            sacc[0] += bv[0]; sacc[1] += bv[1]; sacc[2] += bv[2]; sacc[3] += bv[3];
        }
        __syncthreads();
    }
    size_t gbase = ((size_t)b*16 + kidx)*16384;
    #pragma unroll
    for (int i = 0; i < 8; ++i)
        *(float4*)&Gpart[gbase + (size_t)(khalf*64 + kl + i)*128 + fl] = *(float4*)&acc[i][0];
    if (khalf == 0 && tid < 32)
        *(float4*)&spart[((size_t)b*16 + kidx)*128 + fl] = *(float4*)&sacc[0];
}

__global__ __launch_bounds__(256) void k_reduce_gs(
    const float* __restrict__ Gpart, const float* __restrict__ spart,
    float* __restrict__ G, float* __restrict__ s)
{
    int b = blockIdx.x;
    int idx = blockIdx.y * 1024 + threadIdx.x;
    #pragma unroll
    for (int o = 0; o < 1024; o += 256) {
        float a = 0.f;
        #pragma unroll 4
        for (int i = 0; i < 16; ++i) a += Gpart[((size_t)b*16 + i)*16384 + idx + o];
        G[(size_t)b*16384 + idx + o] = a;
    }
    if (blockIdx.y == 0 && threadIdx.x < 128) {
        float a = 0.f;
        for (int i = 0; i < 16; ++i) a += spart[((size_t)b*16 + i)*128 + threadIdx.x];
        s[b*128 + threadIdx.x] = a;
    }
}

// ------------------------- M = SCALE*(P@G + u⊗s), r = SCALE*(w@G + c*s)
__global__ __launch_bounds__(256) void k_compute_M(
    const float* __restrict__ G, const float* __restrict__ s,
    const float* __restrict__ PTj, const float* __restrict__ uj,
    const float* __restrict__ wj, const float* __restrict__ cj,
    float* __restrict__ Mout, float* __restrict__ rout)
{
    int b = blockIdx.x, khalf = blockIdx.y;
    __shared__ float Gs[32][128];
    __shared__ float Ps[32][64];
    int tid = threadIdx.x;
    int kll = (tid >> 5) * 8, fl = (tid & 31) * 4;
    float acc[8][4] = {};
    for (int kc = 0; kc < 128; kc += 32) {
        for (int e = tid; e < 4096; e += 256)
            Gs[e >> 7][e & 127] = G[(size_t)b*16384 + (size_t)(kc + (e >> 7))*128 + (e & 127)];
        for (int e = tid; e < 2048; e += 256)
            Ps[e >> 6][e & 63] = PTj[(size_t)(kc + (e >> 6))*128 + khalf*64 + (e & 63)];
        __syncthreads();
        #pragma unroll 4
        for (int rr = 0; rr < 32; ++rr) {
            float a[8], bv[4];
            *(float4*)&a[0] = *(const float4*)&Ps[rr][kll];
            *(float4*)&a[4] = *(const float4*)&Ps[rr][kll+4];
            *(float4*)&bv[0] = *(const float4*)&Gs[rr][fl];
            #pragma unroll
            for (int i = 0; i < 8; ++i)
                #pragma unroll
                for (int q = 0; q < 4; ++q)
                    acc[i][q] = fmaf(a[i], bv[q], acc[i][q]);
        }
        __syncthreads();
    }
    int kabs = khalf*64 + kll;
    float sv[4];
    *(float4*)&sv[0] = *(const float4*)&s[b*128 + fl];
    #pragma unroll
    for (int i = 0; i < 8; ++i) {
        float uv2 = uj[kabs + i];
        float4 o;
        o.x = SCALE*(acc[i][0] + uv2*sv[0]);
        o.y = SCALE*(acc[i][1] + uv2*sv[1]);
        o.z = SCALE*(acc[i][2] + uv2*sv[2]);
        o.w = SCALE*(acc[i][3] + uv2*sv[3]);
        *(float4*)&Mout[(size_t)b*16384 + (size_t)(kabs + i)*128 + fl] = o;
    }
    if (khalf == 0 && tid < 128) {
        float rr2 = cj[0] * s[b*128 + tid];
        for (int kp = 0; kp < 128; ++kp)
            rr2 = fmaf(wj[kp], G[(size_t)b*16384 + (size_t)kp*128 + tid], rr2);
        rout[b*128 + tid] = SCALE * rr2;
    }
}

// ----------------------- mid = V@M + r ; optional LN*gl+bl+V, in-place V
__global__ __launch_bounds__(256) void k_mid_ln(
    float* __restrict__ V, const float* __restrict__ M, const float* __restrict__ r,
    const float* __restrict__ glj, const float* __restrict__ blj, int doLN)
{
    int b = blockIdx.x, t0 = blockIdx.y * 64;
    float* Vb = V + (size_t)b*T2*F;
    __shared__ float Ms[32][128];
    __shared__ float Vs[64][36];
    int tid = threadIdx.x;
    int r0 = (tid >> 4) * 4, f0 = (tid & 15) * 8;
    float acc[4][8];
    {
        float rv[8];
        *(float4*)&rv[0] = *(const float4*)&r[b*128 + f0];
        *(float4*)&rv[4] = *(const float4*)&r[b*128 + f0 + 4];
        #pragma unroll
        for (int rr = 0; rr < 4; ++rr)
            #pragma unroll
            for (int i = 0; i < 8; ++i) acc[rr][i] = rv[i];
    }
    for (int kc = 0; kc < 128; kc += 32) {
        for (int e = tid; e < 4096; e += 256)
            Ms[e >> 7][e & 127] = M[(size_t)b*16384 + (size_t)(kc + (e >> 7))*128 + (e & 127)];
        {
            int row = tid >> 2, col = (tid & 3) * 8;
            float4 v0 = *(const float4*)&Vb[(size_t)(t0 + row)*F + kc + col];
            float4 v1 = *(const float4*)&Vb[(size_t)(t0 + row)*F + kc + col + 4];
            *(float4*)&Vs[row][col]     = v0;
            *(float4*)&Vs[row][col + 4] = v1;
        }
        __syncthreads();
        #pragma unroll
        for (int kk = 0; kk < 32; kk += 4) {
            float vvals[4][4];
            #pragma unroll
            for (int rr = 0; rr < 4; ++rr)
                *(float4*)&vvals[rr][0] = *(const float4*)&Vs[r0 + rr][kk];
            #pragma unroll
            for (int k2 = 0; k2 < 4; ++k2) {
                float mrow[8];
                *(float4*)&mrow[0] = *(const float4*)&Ms[kk + k2][f0];
                *(float4*)&mrow[4] = *(const float4*)&Ms[kk + k2][f0 + 4];
                #pragma unroll
                for (int rr = 0; rr < 4; ++rr)
                    #pragma unroll
                    for (int i = 0; i < 8; ++i)
                        acc[rr][i] = fmaf(vvals[rr][k2], mrow[i], acc[rr][i]);
            }
        }
        __syncthreads();
    }
    #pragma unroll
    for (int rr = 0; rr < 4; ++rr) {
        int t = t0 + r0 + rr;
        float outv[8];
        if (doLN) {
            float vo[8];
            *(float4*)&vo[0] = *(const float4*)&Vb[(size_t)t*F + f0];
            *(float4*)&vo[4] = *(const float4*)&Vb[(size_t)t*F + f0 + 4];
            float sm = 0.f;
            #pragma unroll
            for (int i = 0; i < 8; ++i) sm += acc[rr][i];
            sm += __shfl_xor(sm, 1); sm += __shfl_xor(sm, 2);
            sm += __shfl_xor(sm, 4); sm += __shfl_xor(sm, 8);
            float mu = sm * (1.0f/128.0f);
            float dv = 0.f;
            #pragma unroll
            for (int i = 0; i < 8; ++i) { float d = acc[rr][i] - mu; dv = fmaf(d, d, dv); }
            dv += __shfl_xor(dv, 1); dv += __shfl_xor(dv, 2);
            dv += __shfl_xor(dv, 4); dv += __shfl_xor(dv, 8);
            float rs = rsqrtf(dv * (1.0f/128.0f) + EPS);
            #pragma unroll
            for (int i = 0; i < 8; ++i)
                outv[i] = (acc[rr][i] - mu)*rs*glj[f0 + i] + blj[f0 + i] + vo[i];
        } else {
            #pragma unroll
            for (int i = 0; i < 8; ++i) outv[i] = acc[rr][i];
        }
        *(float4*)&Vb[(size_t)t*F + f0]     = *(float4*)&outv[0];
        *(float4*)&Vb[(size_t)t*F + f0 + 4] = *(float4*)&outv[4];
    }
}

// ----------------------------------------- out = DXDY * W2 @ U  (split-K 4)
__global__ __launch_bounds__(256) void k_gemm_out(
    const float* __restrict__ W2m, const float* __restrict__ U, float* __restrict__ opart)
{
    int b = blockIdx.x, nt = blockIdx.y, kq = blockIdx.z;
    int n0 = nt*64, k0 = kq*800;
    const float* Ub = U + (size_t)b*T2*F;
    __shared__ float Ws[8][72];
    __shared__ float Us[8][128];
    int tid = threadIdx.x;
    int nl = (tid >> 5) * 8, f0 = (tid & 31) * 4;
    float acc[8][4] = {};
    for (int t = k0; t < k0 + 800; t += 8) {
        if (tid < 128) {
            int r = tid >> 1, kk = (tid & 1) * 4;
            float4 v = *(const float4*)&W2m[(size_t)(n0 + r)*T2 + t + kk];
            Ws[kk+0][r] = v.x; Ws[kk+1][r] = v.y; Ws[kk+2][r] = v.z; Ws[kk+3][r] = v.w;
        }
        {
            int rr = tid >> 5, col = (tid & 31) * 4;
            *(float4*)&Us[rr][col] = *(const float4*)&Ub[(size_t)(t + rr)*F + col];
        }
        __syncthreads();
        #pragma unroll
        for (int kk = 0; kk < 8; ++kk) {
            float a[8], bv[4];
            *(float4*)&a[0] = *(const float4*)&Ws[kk][nl];
            *(float4*)&a[4] = *(const float4*)&Ws[kk][nl+4];
            *(float4*)&bv[0] = *(const float4*)&Us[kk][f0];
            #pragma unroll
            for (int i = 0; i < 8; ++i)
                #pragma unroll
                for (int q = 0; q < 4; ++q)
                    acc[i][q] = fmaf(a[i], bv[q], acc[i][q]);
        }
        __syncthreads();
    }
    #pragma unroll
    for (int i = 0; i < 8; ++i) {
        size_t base = (size_t)kq*1638400 + ((size_t)b*1600 + n0 + nl + i)*128 + f0;
        float4 o = {acc[i][0], acc[i][1], acc[i][2], acc[i][3]};
        *(float4*)&opart[base] = o;
    }
}

__global__ __launch_bounds__(256) void k_reduce_out(
    const float* __restrict__ opart, float* __restrict__ out)
{
    size_t e = (size_t)blockIdx.x*256 + threadIdx.x;
    out[e] = DXDY * ((opart[e] + opart[e + 1638400]) +
                     (opart[e + 2*1638400] + opart[e + 3*1638400]));
}

// --------------------------------------------------------------- launcher
extern "C" void kernel_launch(void* const* d_in, const int* in_sizes, int n_in,
                              void* d_out, int out_size, void* d_ws, size_t ws_size,
                              hipStream_t stream)
{
    const float* xy  = (const float*)d_in[0];
    const float* kW1 = (const float*)d_in[1];
    const float* kb1 = (const float*)d_in[2];
    const float* kW2 = (const float*)d_in[3];
    const float* kb2 = (const float*)d_in[4];
    const float* kW3 = (const float*)d_in[5];
    const float* kb3 = (const float*)d_in[6];
    const float* fW1 = (const float*)d_in[7];
    const float* fb1 = (const float*)d_in[8];
    const float* fW2 = (const float*)d_in[9];
    const float* fb2 = (const float*)d_in[10];
    const float* fW3 = (const float*)d_in[11];
    const float* fb3 = (const float*)d_in[12];
    const float* Wq  = (const float*)d_in[13];
    const float* bq  = (const float*)d_in[14];
    const float* Wk  = (const float*)d_in[15];
    const float* bk  = (const float*)d_in[16];
    const float* g0  = (const float*)d_in[17];
    const float* b0  = (const float*)d_in[18];
    const float* gl  = (const float*)d_in[19];
    const float* bl  = (const float*)d_in[20];
    float* out = (float*)d_out;

    float* ws      = (float*)d_ws;
    float* W2w     = ws;                        // 5,120,000
    float* V       = W2w + 5120000;             // 3,276,800
    float* PT      = V + 3276800;               // 65,536
    float* uB      = PT + 65536;                // 512
    float* wB      = uB + 512;                  // 512
    float* cB      = wB + 512;                  // 4
    float* lnpart  = cB + 4;                    // 400
    float* lnstats = lnpart + 400;              // 16
    float* Gpart   = lnstats + 16;              // 2,097,152
    float* spart   = Gpart + 2097152;           // 16,384
    float* Gm      = spart + 16384;             // 131,072
    float* sm      = Gm + 131072;               // 1,024
    float* Mm      = sm + 1024;                 // 131,072
    float* rm      = Mm + 131072;               // 1,024
    float* opart   = rm + 1024;                 // 6,553,600
    short* AhF     = (short*)(opart + 6553600); // 4096 shorts
    short* AlF     = AhF + 4096;                // 4096 shorts
    float* uvT     = (float*)(AlF + 4096);      // 204,800 floats

    k_prep_frag<<<1, 512, 0, stream>>>(kW2, fW2, AhF, AlF);
    k_prep_uv<<<dim3(200), 256, 0, stream>>>(kW1, kb1, fW1, fb1, uvT);
    k_mlp_mfma<<<dim3(512), 256, 0, stream>>>(uvT, kb2, kW3, kb3,
                                              fb2, fW3, fb3, AhF, AlF, W2w);
    k_precompute_P<<<dim3(4,9), 256, 0, stream>>>(Wq, bq, Wk, bk, PT, uB, wB, cB);
    k_ln0_part<<<dim3(8,25), 256, 0, stream>>>(xy, lnpart);
    k_ln0_stats<<<1, 64, 0, stream>>>(lnpart, lnstats);
    k_ln0_apply<<<dim3(8,100), 256, 0, stream>>>(xy, g0, b0, lnstats, V);

    for (int j = 0; j < 4; ++j) {
        int rows_per = (j < 3) ? 200 : 100;
        const float* Bmat = (j < 3) ? V : xy;
        k_gemm_gs<<<dim3(16,2,8), 256, 0, stream>>>(V, Bmat, rows_per, Gpart, spart);
        k_reduce_gs<<<dim3(8,16), 256, 0, stream>>>(Gpart, spart, Gm, sm);
        k_compute_M<<<dim3(8,2), 256, 0, stream>>>(Gm, sm, PT + (size_t)j*16384,
                                                   uB + j*128, wB + j*128, cB + j, Mm, rm);
        if (j < 3)
            k_mid_ln<<<dim3(8,50), 256, 0, stream>>>(V, Mm, rm, gl + j*128, bl + j*128, 1);
        else
            k_mid_ln<<<dim3(8,50), 256, 0, stream>>>(V, Mm, rm, gl, bl, 0);
    }

    k_gemm_out<<<dim3(8,25,4), 256, 0, stream>>>(W2w, V, opart);
    k_reduce_out<<<dim3(6400), 256, 0, stream>>>(opart, out);
}

// Round 4
// 703.131 us; speedup vs baseline: 1.7415x; 1.1457x over previous
//
#include <hip/hip_runtime.h>
#include <math.h>

#define NGRID 40
#define NT    1600
#define T2    3200
#define F     128
#define NB    8
#define EPS   1e-5f

__device__ __constant__ const float kINV39 = 1.0f/39.0f;
constexpr float DXDY  = (1.0f/39.0f)*(1.0f/39.0f);
constexpr float SCALE = DXDY * 0.125f;   // DXDY / sqrt(64)

typedef __attribute__((ext_vector_type(8))) short bf16x8;
typedef __attribute__((ext_vector_type(4))) float f32x4;
typedef __attribute__((ext_vector_type(4))) unsigned uint4v;

__device__ __forceinline__ unsigned short f2bf(float f) {
    unsigned u = __builtin_bit_cast(unsigned, f);
    unsigned r = u + 0x7FFFu + ((u >> 16) & 1u);
    return (unsigned short)(r >> 16);
}
__device__ __forceinline__ float bf2f(unsigned short h) {
    unsigned u = ((unsigned)h) << 16;
    return __builtin_bit_cast(float, u);
}

// ---------------- precompute W2-layer A-fragments (hi/lo bf16 split) -------
__global__ __launch_bounds__(512) void k_prep_frag(
    const float* __restrict__ kW2, const float* __restrict__ fW2,
    short* __restrict__ Ah, short* __restrict__ Al)
{
    int tid = threadIdx.x;
    int wid = tid >> 6, lane = tid & 63;
    int mlp = wid >> 2, oc = wid & 3;
    const float* W2 = mlp ? fW2 : kW2;
    int row = lane & 15;            // output index within 16-chunk
    int k0 = (lane >> 4) * 8;       // k range
    #pragma unroll
    for (int i = 0; i < 8; ++i) {
        float w = W2[(size_t)(k0 + i) * 64 + oc * 16 + row];
        unsigned short h = f2bf(w);
        Ah[((mlp*4 + oc)*64 + lane)*8 + i] = (short)h;
        Al[((mlp*4 + oc)*64 + lane)*8 + i] = (short)f2bf(w - bf2f(h));
    }
}

// ---------------- precompute separable layer-1 tables u,v per node --------
__global__ __launch_bounds__(256) void k_prep_uv(
    const float* __restrict__ kW1, const float* __restrict__ kb1,
    const float* __restrict__ fW1, const float* __restrict__ fb1,
    float* __restrict__ uv)
{
    int idx = blockIdx.x * 256 + threadIdx.x;    // 0..51199
    int node = idx >> 5, o = idx & 31;
    float x0 = (float)(node / NGRID) * kINV39;
    float x1 = (float)(node % NGRID) * kINV39;
    uv[idx]          = fmaf(kW1[o], x0, fmaf(kW1[32+o], x1, kb1[o]));
    uv[51200 + idx]  = fmaf(kW1[64+o], x0, kW1[96+o]*x1);
    uv[102400 + idx] = fmaf(fW1[o], x0, fmaf(fW1[32+o], x1, fb1[o]));
    uv[153600 + idx] = fmaf(fW1[64+o], x0, fW1[96+o]*x1);
}

// ---------------- MFMA edge-MLP: grid-stride, persistent frags in VGPR ----
// writes W2 as bf16 hi/lo pair (consumed by MFMA k_gemm_out_mfma)
__global__ __launch_bounds__(256, 2) void k_mlp_mfma(
    const float* __restrict__ uv,
    const float* __restrict__ kb2, const float* __restrict__ kW3,
    const float* __restrict__ kb3,
    const float* __restrict__ fb2, const float* __restrict__ fW3,
    const float* __restrict__ fb3,
    const short* __restrict__ Ah, const short* __restrict__ Al,
    short* __restrict__ W2h, short* __restrict__ W2l)
{
    int tid = threadIdx.x;
    int wid = tid >> 6, lane = tid & 63;
    int c = lane & 15, kg = lane >> 4;
    int k0 = kg * 8;

    bf16x8 AHf[2][4], ALf[2][4];
    float4 B2f[2][4], W3f[2][4];
    #pragma unroll
    for (int mlp = 0; mlp < 2; ++mlp) {
        const float* b2p = mlp ? fb2 : kb2;
        const float* w3p = mlp ? fW3 : kW3;
        #pragma unroll
        for (int oc = 0; oc < 4; ++oc) {
            AHf[mlp][oc] = *(const bf16x8*)&Ah[((mlp*4 + oc)*64 + lane)*8];
            ALf[mlp][oc] = *(const bf16x8*)&Al[((mlp*4 + oc)*64 + lane)*8];
            B2f[mlp][oc] = *(const float4*)&b2p[oc*16 + kg*4];
            W3f[mlp][oc] = *(const float4*)&w3p[oc*16 + kg*4];
        }
    }
    float bias0 = kb3[0], bias1 = fb3[0];

    for (int tile = blockIdx.x*4 + wid; tile < 160000; tile += 2048) {
        int n = tile / 100;
        int m = (tile - n*100)*16 + c;
        float res0, res1;
        #pragma unroll
        for (int mlp = 0; mlp < 2; ++mlp) {
            const float* up = uv + mlp*102400 + n*32 + k0;
            const float* vp = uv + mlp*102400 + 51200 + m*32 + k0;
            float4 ua = *(const float4*)up;
            float4 ub = *(const float4*)(up + 4);
            float4 va = *(const float4*)vp;
            float4 vb = *(const float4*)(vp + 4);
            float h[8] = {ua.x+va.x, ua.y+va.y, ua.z+va.z, ua.w+va.w,
                          ub.x+vb.x, ub.y+vb.y, ub.z+vb.z, ub.w+vb.w};
            #pragma unroll
            for (int i = 0; i < 8; ++i) h[i] = fmaxf(h[i], 0.01f*h[i]);
            unsigned bhp[4], blp[4];
            #pragma unroll
            for (int p = 0; p < 4; ++p) {
                unsigned u0 = __builtin_bit_cast(unsigned, h[2*p]);
                unsigned u1 = __builtin_bit_cast(unsigned, h[2*p+1]);
                bhp[p] = __builtin_amdgcn_perm(u1, u0, 0x07060302u);
                float t0 = __builtin_bit_cast(float, u0 & 0xffff0000u);
                float t1 = __builtin_bit_cast(float, u1 & 0xffff0000u);
                blp[p] = __builtin_amdgcn_perm(
                    __builtin_bit_cast(unsigned, h[2*p+1] - t1),
                    __builtin_bit_cast(unsigned, h[2*p] - t0), 0x07060302u);
            }
            uint4v bhv = {bhp[0], bhp[1], bhp[2], bhp[3]};
            uint4v blv = {blp[0], blp[1], blp[2], blp[3]};
            bf16x8 bh = __builtin_bit_cast(bf16x8, bhv);
            bf16x8 bl = __builtin_bit_cast(bf16x8, blv);
            float acc = 0.f;
            #pragma unroll
            for (int oc = 0; oc < 4; ++oc) {
                f32x4 d = {B2f[mlp][oc].x, B2f[mlp][oc].y,
                           B2f[mlp][oc].z, B2f[mlp][oc].w};
                d = __builtin_amdgcn_mfma_f32_16x16x32_bf16(AHf[mlp][oc], bh, d, 0, 0, 0);
                d = __builtin_amdgcn_mfma_f32_16x16x32_bf16(ALf[mlp][oc], bh, d, 0, 0, 0);
                d = __builtin_amdgcn_mfma_f32_16x16x32_bf16(AHf[mlp][oc], bl, d, 0, 0, 0);
                float w3v[4] = {W3f[mlp][oc].x, W3f[mlp][oc].y,
                                W3f[mlp][oc].z, W3f[mlp][oc].w};
                #pragma unroll
                for (int r = 0; r < 4; ++r)
                    acc = fmaf(fmaxf(d[r], 0.01f*d[r]), w3v[r], acc);
            }
            if (mlp == 0) res0 = acc; else res1 = acc;
        }
        res0 += __shfl_xor(res0, 16); res0 += __shfl_xor(res0, 32);
        res1 += __shfl_xor(res1, 16); res1 += __shfl_xor(res1, 32);
        if (lane < 16) {
            float v0 = res0 + bias0;
            float v1 = res1 + bias1;
            unsigned short h0 = f2bf(v0);
            unsigned short h1 = f2bf(v1);
            W2h[(size_t)n*T2 + m]      = (short)h0;
            W2l[(size_t)n*T2 + m]      = (short)f2bf(v0 - bf2f(h0));
            W2h[(size_t)n*T2 + NT + m] = (short)h1;
            W2l[(size_t)n*T2 + NT + m] = (short)f2bf(v1 - bf2f(h1));
        }
    }
}

// ------------------------------------------------- P^T, u, w, c precompute
__global__ __launch_bounds__(256) void k_precompute_P(
    const float* __restrict__ Wq, const float* __restrict__ bq,
    const float* __restrict__ Wk, const float* __restrict__ bk,
    float* __restrict__ PT, float* __restrict__ uB,
    float* __restrict__ wB, float* __restrict__ cB)
{
    int j = blockIdx.x;
    int part = blockIdx.y;
    const float* wq = Wq + (size_t)j*8*F*64;
    const float* wk = Wk + (size_t)j*8*F*64;
    int tid = threadIdx.x;
    if (part == 8) {
        const float* bqj = bq + j*512;
        const float* bkj = bk + j*512;
        if (tid < 128) {
            int k = tid; float a = 0.f;
            for (int h = 0; h < 8; ++h)
                for (int d = 0; d < 64; ++d)
                    a = fmaf(wq[((size_t)h*F + k)*64 + d], bkj[h*64 + d], a);
            uB[j*128 + k] = a;
        } else {
            int k = tid - 128; float a = 0.f;
            for (int h = 0; h < 8; ++h)
                for (int d = 0; d < 64; ++d)
                    a = fmaf(wk[((size_t)h*F + k)*64 + d], bqj[h*64 + d], a);
            wB[j*128 + k] = a;
        }
        if (tid == 0) {
            float a = 0.f;
            for (int i = 0; i < 512; ++i) a = fmaf(bqj[i], bkj[i], a);
            cB[j] = a;
        }
        return;
    }
    int kp = part*16 + (tid >> 4);
    int k0 = (tid & 15) * 8;
    float acc[8] = {0,0,0,0,0,0,0,0};
    for (int h = 0; h < 8; ++h) {
        const float* wkrow = wk + ((size_t)h*F + kp)*64;
        for (int d = 0; d < 64; ++d) {
            float bv = wkrow[d];
            #pragma unroll
            for (int i = 0; i < 8; ++i)
                acc[i] = fmaf(wq[((size_t)h*F + k0 + i)*64 + d], bv, acc[i]);
        }
    }
    #pragma unroll
    for (int i = 0; i < 8; ++i)
        PT[(size_t)j*16384 + (size_t)kp*128 + k0 + i] = acc[i];
}

// ----------------------------------------------------------- LayerNorm 0
__global__ __launch_bounds__(256) void k_ln0_part(
    const float* __restrict__ xy, float* __restrict__ part)
{
    int b = blockIdx.x, blk = blockIdx.y;
    const float4* p = (const float4*)xy + (size_t)b*102400 + blk*4096 + threadIdx.x;
    float s = 0.f, q = 0.f;
    #pragma unroll
    for (int i = 0; i < 16; ++i) {
        float4 v = p[i*256];
        s += (v.x + v.y) + (v.z + v.w);
        q += (v.x*v.x + v.y*v.y) + (v.z*v.z + v.w*v.w);
    }
    #pragma unroll
    for (int off = 32; off >= 1; off >>= 1) {
        s += __shfl_xor(s, off);
        q += __shfl_xor(q, off);
    }
    __shared__ float ss[4], qs[4];
    int wid = threadIdx.x >> 6;
    if ((threadIdx.x & 63) == 0) { ss[wid] = s; qs[wid] = q; }
    __syncthreads();
    if (threadIdx.x == 0) {
        part[((size_t)b*25 + blk)*2 + 0] = ss[0]+ss[1]+ss[2]+ss[3];
        part[((size_t)b*25 + blk)*2 + 1] = qs[0]+qs[1]+qs[2]+qs[3];
    }
}

__global__ void k_ln0_stats(const float* __restrict__ part, float* __restrict__ stats)
{
    int b = threadIdx.x;
    if (b < NB) {
        float s = 0.f, q = 0.f;
        for (int i = 0; i < 25; ++i) {
            s += part[((size_t)b*25 + i)*2 + 0];
            q += part[((size_t)b*25 + i)*2 + 1];
        }
        float mu  = s * (1.0f/409600.0f);
        float var = q * (1.0f/409600.0f) - mu*mu;
        stats[b*2 + 0] = mu;
        stats[b*2 + 1] = rsqrtf(var + EPS);
    }
}

__global__ __launch_bounds__(256) void k_ln0_apply(
    const float* __restrict__ xy, const float* __restrict__ g0,
    const float* __restrict__ b0, const float* __restrict__ stats,
    float* __restrict__ V)
{
    int b = blockIdx.x;
    float mu = stats[b*2], rs = stats[b*2+1];
    int base = blockIdx.y*1024 + threadIdx.x;
    const float4* xv = (const float4*)xy + (size_t)b*102400;
    const float4* gv = (const float4*)g0;
    const float4* bv = (const float4*)b0;
    float4* Vv = (float4*)V + (size_t)b*102400;
    #pragma unroll
    for (int i = 0; i < 4; ++i) {
        int idx = base + i*256;
        float4 x = xv[idx], g = gv[idx], bb = bv[idx], o;
        o.x = (x.x - mu)*rs*g.x + bb.x;
        o.y = (x.y - mu)*rs*g.y + bb.y;
        o.z = (x.z - mu)*rs*g.z + bb.z;
        o.w = (x.w - mu)*rs*g.w + bb.w;
        Vv[idx] = o;
    }
}

// ------------------------------------------ G = A^T B (split-K) + colsum(B)
__global__ __launch_bounds__(256) void k_gemm_gs(
    const float* __restrict__ A, const float* __restrict__ Bm, int rows_per,
    float* __restrict__ Gpart, float* __restrict__ spart)
{
    int kidx = blockIdx.x, khalf = blockIdx.y, b = blockIdx.z;
    const float* Ab = A  + (size_t)b*T2*F;
    const float* Bb = Bm + (size_t)b*T2*F;
    __shared__ float As[4][64];
    __shared__ float Bs[4][128];
    int tid = threadIdx.x;
    int kl = (tid >> 5) * 8, fl = (tid & 31) * 4;
    float acc[8][4] = {};
    float sacc[4] = {0,0,0,0};
    int t0 = kidx * rows_per;
    for (int t = t0; t < t0 + rows_per; t += 4) {
        As[tid >> 6][tid & 63] = Ab[(size_t)(t + (tid >> 6))*F + khalf*64 + (tid & 63)];
        {
            int e = tid*2, row = e >> 7, col = e & 127;
            *(float2*)&Bs[row][col] = *(const float2*)&Bb[(size_t)(t + row)*F + col];
        }
        __syncthreads();
        #pragma unroll
        for (int rr = 0; rr < 4; ++rr) {
            float a[8], bv[4];
            *(float4*)&a[0] = *(const float4*)&As[rr][kl];
            *(float4*)&a[4] = *(const float4*)&As[rr][kl+4];
            *(float4*)&bv[0] = *(const float4*)&Bs[rr][fl];
            #pragma unroll
            for (int i = 0; i < 8; ++i)
                #pragma unroll
                for (int q = 0; q < 4; ++q)
                    acc[i][q] = fmaf(a[i], bv[q], acc[i][q]);
            sacc[0] += bv[0]; sacc[1] += bv[1]; sacc[2] += bv[2]; sacc[3] += bv[3];
        }
        __syncthreads();
    }
    size_t gbase = ((size_t)b*16 + kidx)*16384;
    #pragma unroll
    for (int i = 0; i < 8; ++i)
        *(float4*)&Gpart[gbase + (size_t)(khalf*64 + kl + i)*128 + fl] = *(float4*)&acc[i][0];
    if (khalf == 0 && tid < 32)
        *(float4*)&spart[((size_t)b*16 + kidx)*128 + fl] = *(float4*)&sacc[0];
}

__global__ __launch_bounds__(256) void k_reduce_gs(
    const float* __restrict__ Gpart, const float* __restrict__ spart,
    float* __restrict__ G, float* __restrict__ s)
{
    int b = blockIdx.x;
    int idx = blockIdx.y * 1024 + threadIdx.x;
    #pragma unroll
    for (int o = 0; o < 1024; o += 256) {
        float a = 0.f;
        #pragma unroll 4
        for (int i = 0; i < 16; ++i) a += Gpart[((size_t)b*16 + i)*16384 + idx + o];
        G[(size_t)b*16384 + idx + o] = a;
    }
    if (blockIdx.y == 0 && threadIdx.x < 128) {
        float a = 0.f;
        for (int i = 0; i < 16; ++i) a += spart[((size_t)b*16 + i)*128 + threadIdx.x];
        s[b*128 + threadIdx.x] = a;
    }
}

// ------------------------- M = SCALE*(P@G + u⊗s), r = SCALE*(w@G + c*s)
__global__ __launch_bounds__(256) void k_compute_M(
    const float* __restrict__ G, const float* __restrict__ s,
    const float* __restrict__ PTj, const float* __restrict__ uj,
    const float* __restrict__ wj, const float* __restrict__ cj,
    float* __restrict__ Mout, float* __restrict__ rout)
{
    int b = blockIdx.x, khalf = blockIdx.y;
    __shared__ float Gs[32][128];
    __shared__ float Ps[32][64];
    int tid = threadIdx.x;
    int kll = (tid >> 5) * 8, fl = (tid & 31) * 4;
    float acc[8][4] = {};
    for (int kc = 0; kc < 128; kc += 32) {
        for (int e = tid; e < 4096; e += 256)
            Gs[e >> 7][e & 127] = G[(size_t)b*16384 + (size_t)(kc + (e >> 7))*128 + (e & 127)];
        for (int e = tid; e < 2048; e += 256)
            Ps[e >> 6][e & 63] = PTj[(size_t)(kc + (e >> 6))*128 + khalf*64 + (e & 63)];
        __syncthreads();
        #pragma unroll 4
        for (int rr = 0; rr < 32; ++rr) {
            float a[8], bv[4];
            *(float4*)&a[0] = *(const float4*)&Ps[rr][kll];
            *(float4*)&a[4] = *(const float4*)&Ps[rr][kll+4];
            *(float4*)&bv[0] = *(const float4*)&Gs[rr][fl];
            #pragma unroll
            for (int i = 0; i < 8; ++i)
                #pragma unroll
                for (int q = 0; q < 4; ++q)
                    acc[i][q] = fmaf(a[i], bv[q], acc[i][q]);
        }
        __syncthreads();
    }
    int kabs = khalf*64 + kll;
    float sv[4];
    *(float4*)&sv[0] = *(const float4*)&s[b*128 + fl];
    #pragma unroll
    for (int i = 0; i < 8; ++i) {
        float uv2 = uj[kabs + i];
        float4 o;
        o.x = SCALE*(acc[i][0] + uv2*sv[0]);
        o.y = SCALE*(acc[i][1] + uv2*sv[1]);
        o.z = SCALE*(acc[i][2] + uv2*sv[2]);
        o.w = SCALE*(acc[i][3] + uv2*sv[3]);
        *(float4*)&Mout[(size_t)b*16384 + (size_t)(kabs + i)*128 + fl] = o;
    }
    if (khalf == 0 && tid < 128) {
        float rr2 = cj[0] * s[b*128 + tid];
        for (int kp = 0; kp < 128; ++kp)
            rr2 = fmaf(wj[kp], G[(size_t)b*16384 + (size_t)kp*128 + tid], rr2);
        rout[b*128 + tid] = SCALE * rr2;
    }
}

// ----------------------- mid = V@M + r ; optional LN*gl+bl+V, in-place V
__global__ __launch_bounds__(256) void k_mid_ln(
    float* __restrict__ V, const float* __restrict__ M, const float* __restrict__ r,
    const float* __restrict__ glj, const float* __restrict__ blj, int doLN)
{
    int b = blockIdx.x, t0 = blockIdx.y * 64;
    float* Vb = V + (size_t)b*T2*F;
    __shared__ float Ms[32][128];
    __shared__ float Vs[64][36];
    int tid = threadIdx.x;
    int r0 = (tid >> 4) * 4, f0 = (tid & 15) * 8;
    float acc[4][8];
    {
        float rv[8];
        *(float4*)&rv[0] = *(const float4*)&r[b*128 + f0];
        *(float4*)&rv[4] = *(const float4*)&r[b*128 + f0 + 4];
        #pragma unroll
        for (int rr = 0; rr < 4; ++rr)
            #pragma unroll
            for (int i = 0; i < 8; ++i) acc[rr][i] = rv[i];
    }
    for (int kc = 0; kc < 128; kc += 32) {
        for (int e = tid; e < 4096; e += 256)
            Ms[e >> 7][e & 127] = M[(size_t)b*16384 + (size_t)(kc + (e >> 7))*128 + (e & 127)];
        {
            int row = tid >> 2, col = (tid & 3) * 8;
            float4 v0 = *(const float4*)&Vb[(size_t)(t0 + row)*F + kc + col];
            float4 v1 = *(const float4*)&Vb[(size_t)(t0 + row)*F + kc + col + 4];
            *(float4*)&Vs[row][col]     = v0;
            *(float4*)&Vs[row][col + 4] = v1;
        }
        __syncthreads();
        #pragma unroll
        for (int kk = 0; kk < 32; kk += 4) {
            float vvals[4][4];
            #pragma unroll
            for (int rr = 0; rr < 4; ++rr)
                *(float4*)&vvals[rr][0] = *(const float4*)&Vs[r0 + rr][kk];
            #pragma unroll
            for (int k2 = 0; k2 < 4; ++k2) {
                float mrow[8];
                *(float4*)&mrow[0] = *(const float4*)&Ms[kk + k2][f0];
                *(float4*)&mrow[4] = *(const float4*)&Ms[kk + k2][f0 + 4];
                #pragma unroll
                for (int rr = 0; rr < 4; ++rr)
                    #pragma unroll
                    for (int i = 0; i < 8; ++i)
                        acc[rr][i] = fmaf(vvals[rr][k2], mrow[i], acc[rr][i]);
            }
        }
        __syncthreads();
    }
    #pragma unroll
    for (int rr = 0; rr < 4; ++rr) {
        int t = t0 + r0 + rr;
        float outv[8];
        if (doLN) {
            float vo[8];
            *(float4*)&vo[0] = *(const float4*)&Vb[(size_t)t*F + f0];
            *(float4*)&vo[4] = *(const float4*)&Vb[(size_t)t*F + f0 + 4];
            float sm = 0.f;
            #pragma unroll
            for (int i = 0; i < 8; ++i) sm += acc[rr][i];
            sm += __shfl_xor(sm, 1); sm += __shfl_xor(sm, 2);
            sm += __shfl_xor(sm, 4); sm += __shfl_xor(sm, 8);
            float mu = sm * (1.0f/128.0f);
            float dv = 0.f;
            #pragma unroll
            for (int i = 0; i < 8; ++i) { float d = acc[rr][i] - mu; dv = fmaf(d, d, dv); }
            dv += __shfl_xor(dv, 1); dv += __shfl_xor(dv, 2);
            dv += __shfl_xor(dv, 4); dv += __shfl_xor(dv, 8);
            float rs = rsqrtf(dv * (1.0f/128.0f) + EPS);
            #pragma unroll
            for (int i = 0; i < 8; ++i)
                outv[i] = (acc[rr][i] - mu)*rs*glj[f0 + i] + blj[f0 + i] + vo[i];
        } else {
            #pragma unroll
            for (int i = 0; i < 8; ++i) outv[i] = acc[rr][i];
        }
        *(float4*)&Vb[(size_t)t*F + f0]     = *(float4*)&outv[0];
        *(float4*)&Vb[(size_t)t*F + f0 + 4] = *(float4*)&outv[4];
    }
}

// ---------------- V (f32 [b][t][f]) -> Ut (bf16 [b][f][t], transposed) ----
__global__ __launch_bounds__(256) void k_cvt_u(
    const float* __restrict__ V, short* __restrict__ Ut)
{
    int b = blockIdx.y;
    int f = threadIdx.x & 127;
    int th = threadIdx.x >> 7;
    int t0 = blockIdx.x*16 + th*8;
    const float* Vb = V + (size_t)b*T2*F;
    short* utb = Ut + (size_t)b*F*T2;
    short tmp[8];
    #pragma unroll
    for (int i = 0; i < 8; ++i)
        tmp[i] = (short)f2bf(Vb[(size_t)(t0+i)*F + f]);
    *(uint4v*)&utb[(size_t)f*T2 + t0] = *(uint4v*)tmp;
}

// ------------- out = DXDY * W2(bf16 hi/lo) @ U(bf16), MFMA, no split-K ----
__global__ __launch_bounds__(256) void k_gemm_out_mfma(
    const short* __restrict__ W2h, const short* __restrict__ W2l,
    const short* __restrict__ Ut, float* __restrict__ out)
{
    int id = blockIdx.x;
    int q = id >> 3;
    if (q >= 25) return;                    // 56 pad blocks exit
    int job = (id & 7) * 25 + q;            // contiguous nt per id%8 class
    int nt = job >> 3, b = job & 7;
    int n0 = nt * 64;
    const short* utb = Ut + (size_t)b*F*T2;

    __shared__ __align__(16) short As_h[2][64][32];
    __shared__ __align__(16) short As_l[2][64][32];
    __shared__ __align__(16) short Bs[2][128][32];

    int tid = threadIdx.x;
    int lane = tid & 63, wid = tid >> 6;
    int wr = wid >> 1, wc = wid & 1;
    int r16 = lane & 15, kg = lane >> 4;

    // staging assignment
    int srow = tid >> 2, sq = tid & 3;      // A: 64 rows x 4 k-quarters
    int sf = tid >> 1, sh = tid & 1;        // B: 128 f x 2 k-halves

    const short* aph = &W2h[(size_t)(n0 + srow)*T2 + sq*8];
    const short* apl = &W2l[(size_t)(n0 + srow)*T2 + sq*8];
    const short* bp  = &utb[(size_t)sf*T2 + sh*16];

    f32x4 acc[2][4];
    #pragma unroll
    for (int i = 0; i < 2; ++i)
        #pragma unroll
        for (int j2 = 0; j2 < 4; ++j2)
            acc[i][j2] = (f32x4){0.f, 0.f, 0.f, 0.f};

    // prologue: stage tile 0 into buf 0
    {
        uint4v ra  = *(const uint4v*)aph;
        uint4v rl  = *(const uint4v*)apl;
        uint4v rb0 = *(const uint4v*)bp;
        uint4v rb1 = *(const uint4v*)(bp + 8);
        *(uint4v*)&As_h[0][srow][sq*8]    = ra;
        *(uint4v*)&As_l[0][srow][sq*8]    = rl;
        *(uint4v*)&Bs[0][sf][sh*16]       = rb0;
        *(uint4v*)&Bs[0][sf][sh*16 + 8]   = rb1;
    }

    for (int it = 0; it < 100; ++it) {
        int cur = it & 1;
        uint4v ra, rl, rb0, rb1;
        // issue next-tile global loads early (latency hides under MFMA)
        if (it < 99) {
            int ko = (it + 1) * 32;
            ra  = *(const uint4v*)(aph + ko);
            rl  = *(const uint4v*)(apl + ko);
            rb0 = *(const uint4v*)(bp + ko);
            rb1 = *(const uint4v*)(bp + ko + 8);
        }
        __syncthreads();
        // fragment reads from current buffer
        bf16x8 ah[2], al[2], bv[4];
        #pragma unroll
        for (int rt = 0; rt < 2; ++rt) {
            ah[rt] = *(const bf16x8*)&As_h[cur][wr*32 + rt*16 + r16][kg*8];
            al[rt] = *(const bf16x8*)&As_l[cur][wr*32 + rt*16 + r16][kg*8];
        }
        #pragma unroll
        for (int ft = 0; ft < 4; ++ft)
            bv[ft] = *(const bf16x8*)&Bs[cur][wc*64 + ft*16 + r16][kg*8];
        // MFMA: 2 row-tiles x 4 col-tiles x (AhB + AlB)
        #pragma unroll
        for (int rt = 0; rt < 2; ++rt)
            #pragma unroll
            for (int ft = 0; ft < 4; ++ft) {
                acc[rt][ft] = __builtin_amdgcn_mfma_f32_16x16x32_bf16(
                    ah[rt], bv[ft], acc[rt][ft], 0, 0, 0);
                acc[rt][ft] = __builtin_amdgcn_mfma_f32_16x16x32_bf16(
                    al[rt], bv[ft], acc[rt][ft], 0, 0, 0);
            }
        // write next buffer (after this iter's reads; safe vs prev via barrier)
        if (it < 99) {
            int nb = cur ^ 1;
            *(uint4v*)&As_h[nb][srow][sq*8]  = ra;
            *(uint4v*)&As_l[nb][srow][sq*8]  = rl;
            *(uint4v*)&Bs[nb][sf][sh*16]     = rb0;
            *(uint4v*)&Bs[nb][sf][sh*16 + 8] = rb1;
        }
    }

    // epilogue: C/D layout col=lane&15, row=(lane>>4)*4+reg
    int rowb = kg * 4;
    #pragma unroll
    for (int rt = 0; rt < 2; ++rt)
        #pragma unroll
        for (int ft = 0; ft < 4; ++ft) {
            #pragma unroll
            for (int reg = 0; reg < 4; ++reg) {
                int n_out = n0 + wr*32 + rt*16 + rowb + reg;
                int f_out = wc*64 + ft*16 + r16;
                out[((size_t)b*NT + n_out)*F + f_out] = DXDY * acc[rt][ft][reg];
            }
        }
}

// --------------------------------------------------------------- launcher
extern "C" void kernel_launch(void* const* d_in, const int* in_sizes, int n_in,
                              void* d_out, int out_size, void* d_ws, size_t ws_size,
                              hipStream_t stream)
{
    const float* xy  = (const float*)d_in[0];
    const float* kW1 = (const float*)d_in[1];
    const float* kb1 = (const float*)d_in[2];
    const float* kW2 = (const float*)d_in[3];
    const float* kb2 = (const float*)d_in[4];
    const float* kW3 = (const float*)d_in[5];
    const float* kb3 = (const float*)d_in[6];
    const float* fW1 = (const float*)d_in[7];
    const float* fb1 = (const float*)d_in[8];
    const float* fW2 = (const float*)d_in[9];
    const float* fb2 = (const float*)d_in[10];
    const float* fW3 = (const float*)d_in[11];
    const float* fb3 = (const float*)d_in[12];
    const float* Wq  = (const float*)d_in[13];
    const float* bq  = (const float*)d_in[14];
    const float* Wk  = (const float*)d_in[15];
    const float* bk  = (const float*)d_in[16];
    const float* g0  = (const float*)d_in[17];
    const float* b0  = (const float*)d_in[18];
    const float* gl  = (const float*)d_in[19];
    const float* bl  = (const float*)d_in[20];
    float* out = (float*)d_out;

    float* ws      = (float*)d_ws;
    short* W2h     = (short*)ws;                 // 5,120,000 shorts
    short* W2l     = W2h + 5120000;              // 5,120,000 shorts
    float* V       = (float*)(W2l + 5120000);    // 3,276,800 floats
    float* PT      = V + 3276800;                // 65,536
    float* uB      = PT + 65536;                 // 512
    float* wB      = uB + 512;                   // 512
    float* cB      = wB + 512;                   // 4
    float* lnpart  = cB + 4;                     // 400
    float* lnstats = lnpart + 400;               // 16
    float* Gpart   = lnstats + 16;               // 2,097,152
    float* spart   = Gpart + 2097152;            // 16,384
    float* Gm      = spart + 16384;              // 131,072
    float* sm      = Gm + 131072;                // 1,024
    float* Mm      = sm + 1024;                  // 131,072
    float* rm      = Mm + 131072;                // 1,024
    short* AhF     = (short*)(rm + 1024);        // 4096 shorts
    short* AlF     = AhF + 4096;                 // 4096 shorts
    float* uvT     = (float*)(AlF + 4096);       // 204,800 floats
    short* Ut      = (short*)(uvT + 204800);     // 3,276,800 shorts

    k_prep_frag<<<1, 512, 0, stream>>>(kW2, fW2, AhF, AlF);
    k_prep_uv<<<dim3(200), 256, 0, stream>>>(kW1, kb1, fW1, fb1, uvT);
    k_mlp_mfma<<<dim3(512), 256, 0, stream>>>(uvT, kb2, kW3, kb3,
                                              fb2, fW3, fb3, AhF, AlF, W2h, W2l);
    k_precompute_P<<<dim3(4,9), 256, 0, stream>>>(Wq, bq, Wk, bk, PT, uB, wB, cB);
    k_ln0_part<<<dim3(8,25), 256, 0, stream>>>(xy, lnpart);
    k_ln0_stats<<<1, 64, 0, stream>>>(lnpart, lnstats);
    k_ln0_apply<<<dim3(8,100), 256, 0, stream>>>(xy, g0, b0, lnstats, V);

    for (int j = 0; j < 4; ++j) {
        int rows_per = (j < 3) ? 200 : 100;
        const float* Bmat = (j < 3) ? V : xy;
        k_gemm_gs<<<dim3(16,2,8), 256, 0, stream>>>(V, Bmat, rows_per, Gpart, spart);
        k_reduce_gs<<<dim3(8,16), 256, 0, stream>>>(Gpart, spart, Gm, sm);
        k_compute_M<<<dim3(8,2), 256, 0, stream>>>(Gm, sm, PT + (size_t)j*16384,
                                                   uB + j*128, wB + j*128, cB + j, Mm, rm);
        if (j < 3)
            k_mid_ln<<<dim3(8,50), 256, 0, stream>>>(V, Mm, rm, gl + j*128, bl + j*128, 1);
        else
            k_mid_ln<<<dim3(8,50), 256, 0, stream>>>(V, Mm, rm, gl, bl, 0);
    }

    k_cvt_u<<<dim3(200, 8), 256, 0, stream>>>(V, Ut);
    k_gemm_out_mfma<<<dim3(256), 256, 0, stream>>>(W2h, W2l, Ut, out);
}

// Round 5
// 548.535 us; speedup vs baseline: 2.2323x; 1.2818x over previous
//
#include <hip/hip_runtime.h>
#include <math.h>

#define NGRID 40
#define NT    1600
#define T2    3200
#define F     128
#define NB    8
#define EPS   1e-5f

__device__ __constant__ const float kINV39 = 1.0f/39.0f;
constexpr float DXDY  = (1.0f/39.0f)*(1.0f/39.0f);
constexpr float SCALE = DXDY * 0.125f;   // DXDY / sqrt(64)

typedef __attribute__((ext_vector_type(8))) short bf16x8;
typedef __attribute__((ext_vector_type(4))) float f32x4;
typedef __attribute__((ext_vector_type(4))) unsigned uint4v;

__device__ __forceinline__ unsigned bitu(float f){ return __builtin_bit_cast(unsigned,f); }
__device__ __forceinline__ float bitf(unsigned u){ return __builtin_bit_cast(float,u); }
__device__ __forceinline__ unsigned short f2bf(float f) {      // round-to-nearest
    unsigned u = bitu(f);
    unsigned r = u + 0x7FFFu + ((u >> 16) & 1u);
    return (unsigned short)(r >> 16);
}
__device__ __forceinline__ float bf2f(unsigned short h) { return bitf(((unsigned)h) << 16); }

// pack pair (a,b) into hi-word uint (trunc) + residual uint
__device__ __forceinline__ void pack_hl(float a, float b, unsigned &h, unsigned &l) {
    unsigned ua = bitu(a), ub = bitu(b);
    h = __builtin_amdgcn_perm(ub, ua, 0x07060302u);
    float ra = a - bitf(ua & 0xffff0000u);
    float rb = b - bitf(ub & 0xffff0000u);
    l = __builtin_amdgcn_perm(bitu(rb), bitu(ra), 0x07060302u);
}
__device__ __forceinline__ void store8u(short* dst, const unsigned* p) {
    uint4v v0 = {p[0], p[1], p[2], p[3]};
    uint4v v1 = {p[4], p[5], p[6], p[7]};
    *(uint4v*)dst = v0;
    *(uint4v*)(dst + 8) = v1;
}
__device__ __forceinline__ void store16u(short* dst, const unsigned* p) {
    store8u(dst, p);
    store8u(dst + 16, p + 8);
}

// ---------------- precompute MLP-W2 A-fragments (hi/lo bf16 split) --------
__global__ __launch_bounds__(512) void k_prep_frag(
    const float* __restrict__ kW2, const float* __restrict__ fW2,
    short* __restrict__ Ah, short* __restrict__ Al)
{
    int tid = threadIdx.x;
    int wid = tid >> 6, lane = tid & 63;
    int mlp = wid >> 2, oc = wid & 3;
    const float* W2 = mlp ? fW2 : kW2;
    int row = lane & 15;
    int k0 = (lane >> 4) * 8;
    #pragma unroll
    for (int i = 0; i < 8; ++i) {
        float w = W2[(size_t)(k0 + i) * 64 + oc * 16 + row];
        unsigned short h = f2bf(w);
        Ah[((mlp*4 + oc)*64 + lane)*8 + i] = (short)h;
        Al[((mlp*4 + oc)*64 + lane)*8 + i] = (short)f2bf(w - bf2f(h));
    }
}

// ---------------- precompute separable layer-1 tables u,v per node --------
__global__ __launch_bounds__(256) void k_prep_uv(
    const float* __restrict__ kW1, const float* __restrict__ kb1,
    const float* __restrict__ fW1, const float* __restrict__ fb1,
    float* __restrict__ uv)
{
    int idx = blockIdx.x * 256 + threadIdx.x;
    int node = idx >> 5, o = idx & 31;
    float x0 = (float)(node / NGRID) * kINV39;
    float x1 = (float)(node % NGRID) * kINV39;
    uv[idx]          = fmaf(kW1[o], x0, fmaf(kW1[32+o], x1, kb1[o]));
    uv[51200 + idx]  = fmaf(kW1[64+o], x0, kW1[96+o]*x1);
    uv[102400 + idx] = fmaf(fW1[o], x0, fmaf(fW1[32+o], x1, fb1[o]));
    uv[153600 + idx] = fmaf(fW1[64+o], x0, fW1[96+o]*x1);
}

// ---------------- MFMA edge-MLP: grid-stride persistent, W2 -> bf16 -------
#define MLPGRID 1536
__global__ __launch_bounds__(256, 2) void k_mlp_mfma(
    const float* __restrict__ uv,
    const float* __restrict__ kb2, const float* __restrict__ kW3,
    const float* __restrict__ kb3,
    const float* __restrict__ fb2, const float* __restrict__ fW3,
    const float* __restrict__ fb3,
    const short* __restrict__ Ah, const short* __restrict__ Al,
    short* __restrict__ W2h)
{
    int tid = threadIdx.x;
    int wid = tid >> 6, lane = tid & 63;
    int c = lane & 15, kg = lane >> 4;
    int k0 = kg * 8;

    bf16x8 AHf[2][4], ALf[2][4];
    float4 B2f[2][4], W3f[2][4];
    #pragma unroll
    for (int mlp = 0; mlp < 2; ++mlp) {
        const float* b2p = mlp ? fb2 : kb2;
        const float* w3p = mlp ? fW3 : kW3;
        #pragma unroll
        for (int oc = 0; oc < 4; ++oc) {
            AHf[mlp][oc] = *(const bf16x8*)&Ah[((mlp*4 + oc)*64 + lane)*8];
            ALf[mlp][oc] = *(const bf16x8*)&Al[((mlp*4 + oc)*64 + lane)*8];
            B2f[mlp][oc] = *(const float4*)&b2p[oc*16 + kg*4];
            W3f[mlp][oc] = *(const float4*)&w3p[oc*16 + kg*4];
        }
    }
    float bias0 = kb3[0], bias1 = fb3[0];

    int tile = blockIdx.x*4 + wid;
    int n = tile / 100;
    int mt = tile - n*100;
    while (tile < 160000) {
        int m = mt*16 + c;
        float res0, res1;
        #pragma unroll
        for (int mlp = 0; mlp < 2; ++mlp) {
            const float* up = uv + mlp*102400 + n*32 + k0;
            const float* vp = uv + mlp*102400 + 51200 + m*32 + k0;
            float4 ua = *(const float4*)up;
            float4 ub = *(const float4*)(up + 4);
            float4 va = *(const float4*)vp;
            float4 vb = *(const float4*)(vp + 4);
            float h[8] = {ua.x+va.x, ua.y+va.y, ua.z+va.z, ua.w+va.w,
                          ub.x+vb.x, ub.y+vb.y, ub.z+vb.z, ub.w+vb.w};
            #pragma unroll
            for (int i = 0; i < 8; ++i) h[i] = fmaxf(h[i], 0.01f*h[i]);
            unsigned bhp[4], blp[4];
            #pragma unroll
            for (int p = 0; p < 4; ++p)
                pack_hl(h[2*p], h[2*p+1], bhp[p], blp[p]);
            uint4v bhv = {bhp[0], bhp[1], bhp[2], bhp[3]};
            uint4v blv = {blp[0], blp[1], blp[2], blp[3]};
            bf16x8 bh = __builtin_bit_cast(bf16x8, bhv);
            bf16x8 bl = __builtin_bit_cast(bf16x8, blv);
            float acc = 0.f;
            #pragma unroll
            for (int oc = 0; oc < 4; ++oc) {
                f32x4 d = {B2f[mlp][oc].x, B2f[mlp][oc].y,
                           B2f[mlp][oc].z, B2f[mlp][oc].w};
                d = __builtin_amdgcn_mfma_f32_16x16x32_bf16(AHf[mlp][oc], bh, d, 0, 0, 0);
                d = __builtin_amdgcn_mfma_f32_16x16x32_bf16(ALf[mlp][oc], bh, d, 0, 0, 0);
                d = __builtin_amdgcn_mfma_f32_16x16x32_bf16(AHf[mlp][oc], bl, d, 0, 0, 0);
                float w3v[4] = {W3f[mlp][oc].x, W3f[mlp][oc].y,
                                W3f[mlp][oc].z, W3f[mlp][oc].w};
                #pragma unroll
                for (int r = 0; r < 4; ++r)
                    acc = fmaf(fmaxf(d[r], 0.01f*d[r]), w3v[r], acc);
            }
            if (mlp == 0) res0 = acc; else res1 = acc;
        }
        res0 += __shfl_xor(res0, 16); res0 += __shfl_xor(res0, 32);
        res1 += __shfl_xor(res1, 16); res1 += __shfl_xor(res1, 32);
        if (lane < 16) {
            W2h[(size_t)n*T2 + m]      = (short)f2bf(res0 + bias0);
            W2h[(size_t)n*T2 + NT + m] = (short)f2bf(res1 + bias1);
        }
        tile += MLPGRID*4;
        n += 61; mt += 44;
        if (mt >= 100) { mt -= 100; ++n; }
    }
}

// --------------------------- P (h/l bf16), u, w, c -------------------------
__global__ __launch_bounds__(256) void k_precompute_P(
    const float* __restrict__ Wq, const float* __restrict__ bq,
    const float* __restrict__ Wk, const float* __restrict__ bk,
    short* __restrict__ Pnh, short* __restrict__ Pnl,
    float* __restrict__ uB, float* __restrict__ wB, float* __restrict__ cB)
{
    int j = blockIdx.x;
    int part = blockIdx.y;
    const float* wq = Wq + (size_t)j*8*F*64;
    const float* wk = Wk + (size_t)j*8*F*64;
    int tid = threadIdx.x;
    if (part == 8) {
        const float* bqj = bq + j*512;
        const float* bkj = bk + j*512;
        if (tid < 128) {
            int k = tid; float a = 0.f;
            for (int h = 0; h < 8; ++h)
                for (int d = 0; d < 64; ++d)
                    a = fmaf(wq[((size_t)h*F + k)*64 + d], bkj[h*64 + d], a);
            uB[j*128 + k] = a;
        } else {
            int k = tid - 128; float a = 0.f;
            for (int h = 0; h < 8; ++h)
                for (int d = 0; d < 64; ++d)
                    a = fmaf(wk[((size_t)h*F + k)*64 + d], bqj[h*64 + d], a);
            wB[j*128 + k] = a;
        }
        if (tid == 0) {
            float a = 0.f;
            for (int i = 0; i < 512; ++i) a = fmaf(bqj[i], bkj[i], a);
            cB[j] = a;
        }
        return;
    }
    int kp = part*16 + (tid >> 4);
    int k0 = (tid & 15) * 8;
    float acc[8] = {0,0,0,0,0,0,0,0};
    for (int h = 0; h < 8; ++h) {
        const float* wkrow = wk + ((size_t)h*F + kp)*64;
        for (int d = 0; d < 64; ++d) {
            float bv = wkrow[d];
            #pragma unroll
            for (int i = 0; i < 8; ++i)
                acc[i] = fmaf(wq[((size_t)h*F + k0 + i)*64 + d], bv, acc[i]);
        }
    }
    #pragma unroll
    for (int i = 0; i < 8; ++i) {
        float val = acc[i];                     // P[k0+i][kp]
        short hs = (short)(bitu(val) >> 16);    // trunc hi
        float rem = val - bitf(bitu(val) & 0xffff0000u);
        short ls = (short)(bitu(rem) >> 16);
        Pnh[((size_t)j*128 + k0 + i)*128 + kp] = hs;
        Pnl[((size_t)j*128 + k0 + i)*128 + kp] = ls;
    }
}

// ----------------------------------------------------------- LayerNorm 0
__global__ __launch_bounds__(256) void k_ln0_part(
    const float* __restrict__ xy, float* __restrict__ part)
{
    int b = blockIdx.x, blk = blockIdx.y;
    const float4* p = (const float4*)xy + (size_t)b*102400 + blk*4096 + threadIdx.x;
    float s = 0.f, q = 0.f;
    #pragma unroll
    for (int i = 0; i < 16; ++i) {
        float4 v = p[i*256];
        s += (v.x + v.y) + (v.z + v.w);
        q += (v.x*v.x + v.y*v.y) + (v.z*v.z + v.w*v.w);
    }
    #pragma unroll
    for (int off = 32; off >= 1; off >>= 1) {
        s += __shfl_xor(s, off);
        q += __shfl_xor(q, off);
    }
    __shared__ float ss[4], qs[4];
    int wid = threadIdx.x >> 6;
    if ((threadIdx.x & 63) == 0) { ss[wid] = s; qs[wid] = q; }
    __syncthreads();
    if (threadIdx.x == 0) {
        part[((size_t)b*25 + blk)*2 + 0] = ss[0]+ss[1]+ss[2]+ss[3];
        part[((size_t)b*25 + blk)*2 + 1] = qs[0]+qs[1]+qs[2]+qs[3];
    }
}

__global__ void k_ln0_stats(const float* __restrict__ part, float* __restrict__ stats)
{
    int b = threadIdx.x;
    if (b < NB) {
        float s = 0.f, q = 0.f;
        for (int i = 0; i < 25; ++i) {
            s += part[((size_t)b*25 + i)*2 + 0];
            q += part[((size_t)b*25 + i)*2 + 1];
        }
        float mu  = s * (1.0f/409600.0f);
        float var = q * (1.0f/409600.0f) - mu*mu;
        stats[b*2 + 0] = mu;
        stats[b*2 + 1] = rsqrtf(var + EPS);
    }
}

// ----------- LN0 apply -> V0 as bf16 h/l in both layouts + s0 partials ----
__global__ __launch_bounds__(256) void k_ln0_apply(
    const float* __restrict__ xy, const float* __restrict__ g0,
    const float* __restrict__ b0, const float* __restrict__ stats,
    short* __restrict__ Vbh, short* __restrict__ Vbl,
    short* __restrict__ Vbth, short* __restrict__ Vbtl,
    float* __restrict__ spartV)
{
    int tgrp = blockIdx.x, b = blockIdx.y;
    float mu = stats[b*2], rs = stats[b*2+1];
    __shared__ float T[64][132];
    int tid = threadIdx.x;
    int r = tid >> 2, q = tid & 3;
    int f2 = tid >> 1, half = tid & 1;
    #pragma unroll
    for (int p = 0; p < 2; ++p) {
        int t0 = tgrp*128 + p*64;
        {
            int t = t0 + r;
            const float* xp = xy + ((size_t)b*T2 + t)*F + q*32;
            const float* gp = g0 + (size_t)t*F + q*32;
            const float* bp = b0 + (size_t)t*F + q*32;
            unsigned ph[16], pl[16];
            #pragma unroll
            for (int i = 0; i < 32; i += 4) {
                float4 x = *(const float4*)&xp[i];
                float4 g = *(const float4*)&gp[i];
                float4 bb = *(const float4*)&bp[i];
                float o0 = (x.x - mu)*rs*g.x + bb.x;
                float o1 = (x.y - mu)*rs*g.y + bb.y;
                float o2 = (x.z - mu)*rs*g.z + bb.z;
                float o3 = (x.w - mu)*rs*g.w + bb.w;
                T[r][q*32+i] = o0; T[r][q*32+i+1] = o1;
                T[r][q*32+i+2] = o2; T[r][q*32+i+3] = o3;
                pack_hl(o0, o1, ph[i>>1], pl[i>>1]);
                pack_hl(o2, o3, ph[(i>>1)+1], pl[(i>>1)+1]);
            }
            size_t ob = ((size_t)b*T2 + t)*F + q*32;
            store16u(&Vbh[ob], ph);
            store16u(&Vbl[ob], pl);
        }
        __syncthreads();
        {
            float sacc = 0.f;
            unsigned ph[16], pl[16];
            #pragma unroll
            for (int i = 0; i < 32; i += 2) {
                float v0 = T[half*32 + i][f2];
                float v1 = T[half*32 + i + 1][f2];
                sacc += v0 + v1;
                pack_hl(v0, v1, ph[i>>1], pl[i>>1]);
            }
            size_t ob = ((size_t)b*F + f2)*T2 + t0 + half*32;
            store16u(&Vbth[ob], ph);
            store16u(&Vbtl[ob], pl);
            spartV[((size_t)b*100 + (tgrp*2+p)*2 + half)*128 + f2] = sacc;
        }
        __syncthreads();
    }
}

// ----------- xy[:, :1600] -> transposed bf16 h/l + s2 partials ------------
__global__ __launch_bounds__(256) void k_prep_xyt(
    const float* __restrict__ xy,
    short* __restrict__ xyTh, short* __restrict__ xyTl,
    float* __restrict__ s2part)
{
    int tgrp = blockIdx.x, b = blockIdx.y;
    __shared__ float T[64][132];
    int tid = threadIdx.x;
    int r = tid >> 2, q = tid & 3;
    int f2 = tid >> 1, half = tid & 1;
    int t0 = tgrp*64;
    {
        const float* xp = xy + ((size_t)b*T2 + t0 + r)*F + q*32;
        #pragma unroll
        for (int i = 0; i < 32; i += 4)
            *(float4*)&T[r][q*32+i] = *(const float4*)&xp[i];
    }
    __syncthreads();
    {
        float sacc = 0.f;
        unsigned ph[16], pl[16];
        #pragma unroll
        for (int i = 0; i < 32; i += 2) {
            float v0 = T[half*32 + i][f2];
            float v1 = T[half*32 + i + 1][f2];
            sacc += v0 + v1;
            pack_hl(v0, v1, ph[i>>1], pl[i>>1]);
        }
        size_t ob = ((size_t)b*F + f2)*1600 + t0 + half*32;
        store16u(&xyTh[ob], ph);
        store16u(&xyTl[ob], pl);
        s2part[((size_t)b*50 + tgrp*2 + half)*128 + f2] = sacc;
    }
}

// ------------- G partials: D[r][c] = sum_t X[r][t] X[c][t]  (j<3) ---------
__global__ __launch_bounds__(256) void k_gemm_g_sym(
    const short* __restrict__ Xh, const short* __restrict__ Xl,
    float* __restrict__ Gpart)
{
    int split = blockIdx.x, b = blockIdx.y;
    int t0 = split*128;
    __shared__ __align__(16) short Sh[2][128][40], Sl[2][128][40];
    int tid = threadIdx.x;
    int lane = tid & 63, wid = tid >> 6;
    int wr = wid >> 1, wc = wid & 1;
    int r16 = lane & 15, kg = lane >> 4;
    int sf = tid >> 1, th = tid & 1;

    const short* ph_ = Xh + ((size_t)b*F + sf)*T2 + t0 + th*16;
    const short* pl_ = Xl + ((size_t)b*F + sf)*T2 + t0 + th*16;

    f32x4 acc[4][4];
    #pragma unroll
    for (int i = 0; i < 4; ++i)
        #pragma unroll
        for (int j2 = 0; j2 < 4; ++j2)
            acc[i][j2] = (f32x4){0.f,0.f,0.f,0.f};

    {
        uint4v h0 = *(const uint4v*)ph_,      h1 = *(const uint4v*)(ph_ + 8);
        uint4v l0 = *(const uint4v*)pl_,      l1 = *(const uint4v*)(pl_ + 8);
        *(uint4v*)&Sh[0][sf][th*16]     = h0; *(uint4v*)&Sh[0][sf][th*16+8] = h1;
        *(uint4v*)&Sl[0][sf][th*16]     = l0; *(uint4v*)&Sl[0][sf][th*16+8] = l1;
    }
    #pragma unroll
    for (int ks = 0; ks < 4; ++ks) {
        int cur = ks & 1;
        uint4v h0, h1, l0, l1;
        if (ks < 3) {
            int ko = (ks+1)*32;
            h0 = *(const uint4v*)(ph_ + ko); h1 = *(const uint4v*)(ph_ + ko + 8);
            l0 = *(const uint4v*)(pl_ + ko); l1 = *(const uint4v*)(pl_ + ko + 8);
        }
        __syncthreads();
        bf16x8 ah[4], al[4], bh[4], bl[4];
        #pragma unroll
        for (int i = 0; i < 4; ++i) {
            ah[i] = *(const bf16x8*)&Sh[cur][wr*64 + i*16 + r16][kg*8];
            al[i] = *(const bf16x8*)&Sl[cur][wr*64 + i*16 + r16][kg*8];
            bh[i] = *(const bf16x8*)&Sh[cur][wc*64 + i*16 + r16][kg*8];
            bl[i] = *(const bf16x8*)&Sl[cur][wc*64 + i*16 + r16][kg*8];
        }
        #pragma unroll
        for (int i = 0; i < 4; ++i)
            #pragma unroll
            for (int j2 = 0; j2 < 4; ++j2) {
                acc[i][j2] = __builtin_amdgcn_mfma_f32_16x16x32_bf16(ah[i], bh[j2], acc[i][j2], 0,0,0);
                acc[i][j2] = __builtin_amdgcn_mfma_f32_16x16x32_bf16(al[i], bh[j2], acc[i][j2], 0,0,0);
                acc[i][j2] = __builtin_amdgcn_mfma_f32_16x16x32_bf16(ah[i], bl[j2], acc[i][j2], 0,0,0);
            }
        if (ks < 3) {
            int nb = cur ^ 1;
            *(uint4v*)&Sh[nb][sf][th*16]     = h0; *(uint4v*)&Sh[nb][sf][th*16+8] = h1;
            *(uint4v*)&Sl[nb][sf][th*16]     = l0; *(uint4v*)&Sl[nb][sf][th*16+8] = l1;
        }
    }
    size_t gb = ((size_t)b*25 + split)*16384;
    #pragma unroll
    for (int i = 0; i < 4; ++i)
        #pragma unroll
        for (int j2 = 0; j2 < 4; ++j2)
            #pragma unroll
            for (int reg = 0; reg < 4; ++reg)
                Gpart[gb + (size_t)(wr*64 + i*16 + kg*4 + reg)*128 + wc*64 + j2*16 + r16]
                    = acc[i][j2][reg];
}

// ------- G2^T partials: D[r][c] = sum_t A[r][t] B[c][t]  (j==3) -----------
__global__ __launch_bounds__(256) void k_gemm_g_asym(
    const short* __restrict__ Ah_, const short* __restrict__ Al_,
    const short* __restrict__ Bh_, const short* __restrict__ Bl_,
    float* __restrict__ Gpart)
{
    int split = blockIdx.x, b = blockIdx.y;
    int t0 = split*64;
    __shared__ __align__(16) short Ahs[128][40], Als[128][40], Bhs[128][40], Bls[128][40];
    int tid = threadIdx.x;
    int lane = tid & 63, wid = tid >> 6;
    int wr = wid >> 1, wc = wid & 1;
    int r16 = lane & 15, kg = lane >> 4;
    int sf = tid >> 1, th = tid & 1;

    const short* pah = Ah_ + ((size_t)b*F + sf)*1600 + t0 + th*16;
    const short* pal = Al_ + ((size_t)b*F + sf)*1600 + t0 + th*16;
    const short* pbh = Bh_ + ((size_t)b*F + sf)*T2   + t0 + th*16;
    const short* pbl = Bl_ + ((size_t)b*F + sf)*T2   + t0 + th*16;

    f32x4 acc[4][4];
    #pragma unroll
    for (int i = 0; i < 4; ++i)
        #pragma unroll
        for (int j2 = 0; j2 < 4; ++j2)
            acc[i][j2] = (f32x4){0.f,0.f,0.f,0.f};

    #pragma unroll
    for (int ks = 0; ks < 2; ++ks) {
        int ko = ks*32;
        if (ks) __syncthreads();
        *(uint4v*)&Ahs[sf][th*16]   = *(const uint4v*)(pah + ko);
        *(uint4v*)&Ahs[sf][th*16+8] = *(const uint4v*)(pah + ko + 8);
        *(uint4v*)&Als[sf][th*16]   = *(const uint4v*)(pal + ko);
        *(uint4v*)&Als[sf][th*16+8] = *(const uint4v*)(pal + ko + 8);
        *(uint4v*)&Bhs[sf][th*16]   = *(const uint4v*)(pbh + ko);
        *(uint4v*)&Bhs[sf][th*16+8] = *(const uint4v*)(pbh + ko + 8);
        *(uint4v*)&Bls[sf][th*16]   = *(const uint4v*)(pbl + ko);
        *(uint4v*)&Bls[sf][th*16+8] = *(const uint4v*)(pbl + ko + 8);
        __syncthreads();
        bf16x8 ah[4], al[4], bh[4], bl[4];
        #pragma unroll
        for (int i = 0; i < 4; ++i) {
            ah[i] = *(const bf16x8*)&Ahs[wr*64 + i*16 + r16][kg*8];
            al[i] = *(const bf16x8*)&Als[wr*64 + i*16 + r16][kg*8];
            bh[i] = *(const bf16x8*)&Bhs[wc*64 + i*16 + r16][kg*8];
            bl[i] = *(const bf16x8*)&Bls[wc*64 + i*16 + r16][kg*8];
        }
        #pragma unroll
        for (int i = 0; i < 4; ++i)
            #pragma unroll
            for (int j2 = 0; j2 < 4; ++j2) {
                acc[i][j2] = __builtin_amdgcn_mfma_f32_16x16x32_bf16(ah[i], bh[j2], acc[i][j2], 0,0,0);
                acc[i][j2] = __builtin_amdgcn_mfma_f32_16x16x32_bf16(al[i], bh[j2], acc[i][j2], 0,0,0);
                acc[i][j2] = __builtin_amdgcn_mfma_f32_16x16x32_bf16(ah[i], bl[j2], acc[i][j2], 0,0,0);
            }
    }
    size_t gb = ((size_t)b*25 + split)*16384;
    #pragma unroll
    for (int i = 0; i < 4; ++i)
        #pragma unroll
        for (int j2 = 0; j2 < 4; ++j2)
            #pragma unroll
            for (int reg = 0; reg < 4; ++reg)
                Gpart[gb + (size_t)(wr*64 + i*16 + kg*4 + reg)*128 + wc*64 + j2*16 + r16]
                    = acc[i][j2][reg];
}

// --------- reduce G partials -> Gb h/l bf16 + rpart[f] = sum w[kp]G -------
__global__ __launch_bounds__(256) void k_gred(
    const float* __restrict__ Gpart, const float* __restrict__ wj,
    short* __restrict__ Gbh, short* __restrict__ Gbl, float* __restrict__ rpart)
{
    int part = blockIdx.x, b = blockIdx.y;
    int tid = threadIdx.x;
    int e0 = part*2048 + tid*8;
    float a[8] = {0,0,0,0,0,0,0,0};
    for (int i = 0; i < 25; ++i) {
        const float* p = Gpart + ((size_t)b*25 + i)*16384 + e0;
        float4 x0 = *(const float4*)p;
        float4 x1 = *(const float4*)(p + 4);
        a[0] += x0.x; a[1] += x0.y; a[2] += x0.z; a[3] += x0.w;
        a[4] += x1.x; a[5] += x1.y; a[6] += x1.z; a[7] += x1.w;
    }
    unsigned ph[4], pl[4];
    #pragma unroll
    for (int i = 0; i < 8; i += 2) pack_hl(a[i], a[i+1], ph[i>>1], pl[i>>1]);
    uint4v vh = {ph[0],ph[1],ph[2],ph[3]};
    uint4v vl = {pl[0],pl[1],pl[2],pl[3]};
    *(uint4v*)&Gbh[(size_t)b*16384 + e0] = vh;
    *(uint4v*)&Gbl[(size_t)b*16384 + e0] = vl;

    int c0 = e0 & 127;
    float4 w0 = *(const float4*)&wj[c0];
    float4 w1 = *(const float4*)&wj[c0 + 4];
    float pr = a[0]*w0.x + a[1]*w0.y + a[2]*w0.z + a[3]*w0.w
             + a[4]*w1.x + a[5]*w1.y + a[6]*w1.z + a[7]*w1.w;
    pr += __shfl_xor(pr, 1); pr += __shfl_xor(pr, 2);
    pr += __shfl_xor(pr, 4); pr += __shfl_xor(pr, 8);
    if ((tid & 15) == 0) rpart[b*128 + (e0 >> 7)] = pr;
}

// -------- M = SCALE(P@G + u⊗s) via MFMA -> Mt h/l transposed; rm ----------
struct CMStage {
    short Psh[2][64][40], Psl[2][64][40];
    short Bsh[2][128][40], Bsl[2][128][40];
};
__global__ __launch_bounds__(256) void k_computeM(
    const short* __restrict__ Gbh, const short* __restrict__ Gbl,
    const float* __restrict__ spart, int np,
    const short* __restrict__ Pjh, const short* __restrict__ Pjl,
    const float* __restrict__ uj, const float* __restrict__ cj,
    const float* __restrict__ rpart,
    short* __restrict__ Mth, short* __restrict__ Mtl, float* __restrict__ rm)
{
    int kh = blockIdx.x, b = blockIdx.y;
    __shared__ __align__(16) char smem[sizeof(CMStage)];
    CMStage& S = *(CMStage*)smem;
    float (*T)[132] = (float(*)[132])smem;
    __shared__ float sv[128];

    int tid = threadIdx.x;
    int lane = tid & 63, wid = tid >> 6;
    int wr = wid >> 1, wc = wid & 1;
    int r16 = lane & 15, kg = lane >> 4;
    int st = tid >> 2, sq = tid & 3;
    int sf = tid >> 1, sh2 = tid & 1;

    if (tid < 128) {
        float s = 0.f;
        for (int i = 0; i < np; ++i) s += spart[((size_t)b*np + i)*128 + tid];
        sv[tid] = s;
        if (kh == 0) rm[b*128 + tid] = SCALE*(rpart[b*128 + tid] + cj[0]*s);
    }

    const short* pah = Pjh + (size_t)(kh*64 + st)*128 + sq*8;
    const short* pal = Pjl + (size_t)(kh*64 + st)*128 + sq*8;
    const short* pbh = Gbh + ((size_t)b*F + sf)*128 + sh2*16;
    const short* pbl = Gbl + ((size_t)b*F + sf)*128 + sh2*16;

    f32x4 acc[2][4];
    #pragma unroll
    for (int i = 0; i < 2; ++i)
        #pragma unroll
        for (int j2 = 0; j2 < 4; ++j2)
            acc[i][j2] = (f32x4){0.f,0.f,0.f,0.f};

    {
        *(uint4v*)&S.Psh[0][st][sq*8]      = *(const uint4v*)pah;
        *(uint4v*)&S.Psl[0][st][sq*8]      = *(const uint4v*)pal;
        *(uint4v*)&S.Bsh[0][sf][sh2*16]    = *(const uint4v*)pbh;
        *(uint4v*)&S.Bsh[0][sf][sh2*16+8]  = *(const uint4v*)(pbh + 8);
        *(uint4v*)&S.Bsl[0][sf][sh2*16]    = *(const uint4v*)pbl;
        *(uint4v*)&S.Bsl[0][sf][sh2*16+8]  = *(const uint4v*)(pbl + 8);
    }
    #pragma unroll
    for (int ks = 0; ks < 4; ++ks) {
        int cur = ks & 1;
        uint4v a0, a1, b0, b1, b2, b3;
        if (ks < 3) {
            int ko = (ks+1)*32;
            a0 = *(const uint4v*)(pah + ko); a1 = *(const uint4v*)(pal + ko);
            b0 = *(const uint4v*)(pbh + ko); b1 = *(const uint4v*)(pbh + ko + 8);
            b2 = *(const uint4v*)(pbl + ko); b3 = *(const uint4v*)(pbl + ko + 8);
        }
        __syncthreads();
        bf16x8 ah[2], al[2], bh[4], bl[4];
        #pragma unroll
        for (int i = 0; i < 2; ++i) {
            ah[i] = *(const bf16x8*)&S.Psh[cur][wr*32 + i*16 + r16][kg*8];
            al[i] = *(const bf16x8*)&S.Psl[cur][wr*32 + i*16 + r16][kg*8];
        }
        #pragma unroll
        for (int j2 = 0; j2 < 4; ++j2) {
            bh[j2] = *(const bf16x8*)&S.Bsh[cur][wc*64 + j2*16 + r16][kg*8];
            bl[j2] = *(const bf16x8*)&S.Bsl[cur][wc*64 + j2*16 + r16][kg*8];
        }
        #pragma unroll
        for (int i = 0; i < 2; ++i)
            #pragma unroll
            for (int j2 = 0; j2 < 4; ++j2) {
                acc[i][j2] = __builtin_amdgcn_mfma_f32_16x16x32_bf16(ah[i], bh[j2], acc[i][j2], 0,0,0);
                acc[i][j2] = __builtin_amdgcn_mfma_f32_16x16x32_bf16(al[i], bh[j2], acc[i][j2], 0,0,0);
                acc[i][j2] = __builtin_amdgcn_mfma_f32_16x16x32_bf16(ah[i], bl[j2], acc[i][j2], 0,0,0);
            }
        if (ks < 3) {
            int nb = cur ^ 1;
            *(uint4v*)&S.Psh[nb][st][sq*8]     = a0;
            *(uint4v*)&S.Psl[nb][st][sq*8]     = a1;
            *(uint4v*)&S.Bsh[nb][sf][sh2*16]   = b0;
            *(uint4v*)&S.Bsh[nb][sf][sh2*16+8] = b1;
            *(uint4v*)&S.Bsl[nb][sf][sh2*16]   = b2;
            *(uint4v*)&S.Bsl[nb][sf][sh2*16+8] = b3;
        }
    }
    float uval[2][4], svv[4];
    #pragma unroll
    for (int i = 0; i < 2; ++i)
        #pragma unroll
        for (int reg = 0; reg < 4; ++reg)
            uval[i][reg] = uj[kh*64 + wr*32 + i*16 + kg*4 + reg];
    #pragma unroll
    for (int j2 = 0; j2 < 4; ++j2) svv[j2] = sv[wc*64 + j2*16 + r16];
    __syncthreads();
    #pragma unroll
    for (int i = 0; i < 2; ++i)
        #pragma unroll
        for (int j2 = 0; j2 < 4; ++j2)
            #pragma unroll
            for (int reg = 0; reg < 4; ++reg)
                T[wr*32 + i*16 + kg*4 + reg][wc*64 + j2*16 + r16]
                    = SCALE*(acc[i][j2][reg] + uval[i][reg]*svv[j2]);
    __syncthreads();
    {
        int f2 = tid >> 1, half = tid & 1;
        unsigned ph[16], pl[16];
        #pragma unroll
        for (int i = 0; i < 32; i += 2) {
            float v0 = T[half*32 + i][f2];
            float v1 = T[half*32 + i + 1][f2];
            pack_hl(v0, v1, ph[i>>1], pl[i>>1]);
        }
        size_t ob = ((size_t)b*F + f2)*F + kh*64 + half*32;
        store16u(&Mth[ob], ph);
        store16u(&Mtl[ob], pl);
    }
}

// -------- mid = V@M + r; optional LN+residual; emit h/l dual-layout -------
struct MidStage {
    short Ash[2][64][40], Asl[2][64][40];
    short Bsh[2][128][40], Bsl[2][128][40];
};
__global__ __launch_bounds__(256) void k_mid(
    short* __restrict__ Vbh, short* __restrict__ Vbl,
    const short* __restrict__ Mth, const short* __restrict__ Mtl,
    const float* __restrict__ rm,
    const float* __restrict__ glj, const float* __restrict__ blj, int doLN,
    short* __restrict__ OTh, short* __restrict__ OTl,
    float* __restrict__ spartN)
{
    int tblk = blockIdx.x, b = blockIdx.y;
    int t0 = tblk * 64;
    __shared__ __align__(16) char smem[sizeof(MidStage)];
    MidStage& S = *(MidStage*)smem;
    float (*T)[132] = (float(*)[132])smem;

    int tid = threadIdx.x;
    int lane = tid & 63, wid = tid >> 6;
    int wr = wid >> 1, wc = wid & 1;
    int r16 = lane & 15, kg = lane >> 4;
    int st = tid >> 2, sq = tid & 3;
    int sf = tid >> 1, sh2 = tid & 1;

    const short* pah = Vbh + ((size_t)b*T2 + t0 + st)*F + sq*8;
    const short* pal = Vbl + ((size_t)b*T2 + t0 + st)*F + sq*8;
    const short* pbh = Mth + ((size_t)b*F + sf)*F + sh2*16;
    const short* pbl = Mtl + ((size_t)b*F + sf)*F + sh2*16;

    f32x4 acc[2][4];
    #pragma unroll
    for (int i = 0; i < 2; ++i)
        #pragma unroll
        for (int j2 = 0; j2 < 4; ++j2)
            acc[i][j2] = (f32x4){0.f,0.f,0.f,0.f};

    {
        *(uint4v*)&S.Ash[0][st][sq*8]      = *(const uint4v*)pah;
        *(uint4v*)&S.Asl[0][st][sq*8]      = *(const uint4v*)pal;
        *(uint4v*)&S.Bsh[0][sf][sh2*16]    = *(const uint4v*)pbh;
        *(uint4v*)&S.Bsh[0][sf][sh2*16+8]  = *(const uint4v*)(pbh + 8);
        *(uint4v*)&S.Bsl[0][sf][sh2*16]    = *(const uint4v*)pbl;
        *(uint4v*)&S.Bsl[0][sf][sh2*16+8]  = *(const uint4v*)(pbl + 8);
    }
    #pragma unroll
    for (int ks = 0; ks < 4; ++ks) {
        int cur = ks & 1;
        uint4v a0, a1, b0, b1, b2, b3;
        if (ks < 3) {
            int ko = (ks+1)*32;
            a0 = *(const uint4v*)(pah + ko); a1 = *(const uint4v*)(pal + ko);
            b0 = *(const uint4v*)(pbh + ko); b1 = *(const uint4v*)(pbh + ko + 8);
            b2 = *(const uint4v*)(pbl + ko); b3 = *(const uint4v*)(pbl + ko + 8);
        }
        __syncthreads();
        bf16x8 ah[2], al[2], bh[4], bl[4];
        #pragma unroll
        for (int i = 0; i < 2; ++i) {
            ah[i] = *(const bf16x8*)&S.Ash[cur][wr*32 + i*16 + r16][kg*8];
            al[i] = *(const bf16x8*)&S.Asl[cur][wr*32 + i*16 + r16][kg*8];
        }
        #pragma unroll
        for (int j2 = 0; j2 < 4; ++j2) {
            bh[j2] = *(const bf16x8*)&S.Bsh[cur][wc*64 + j2*16 + r16][kg*8];
            bl[j2] = *(const bf16x8*)&S.Bsl[cur][wc*64 + j2*16 + r16][kg*8];
        }
        #pragma unroll
        for (int i = 0; i < 2; ++i)
            #pragma unroll
            for (int j2 = 0; j2 < 4; ++j2) {
                acc[i][j2] = __builtin_amdgcn_mfma_f32_16x16x32_bf16(ah[i], bh[j2], acc[i][j2], 0,0,0);
                acc[i][j2] = __builtin_amdgcn_mfma_f32_16x16x32_bf16(al[i], bh[j2], acc[i][j2], 0,0,0);
                acc[i][j2] = __builtin_amdgcn_mfma_f32_16x16x32_bf16(ah[i], bl[j2], acc[i][j2], 0,0,0);
            }
        if (ks < 3) {
            int nb = cur ^ 1;
            *(uint4v*)&S.Ash[nb][st][sq*8]     = a0;
            *(uint4v*)&S.Asl[nb][st][sq*8]     = a1;
            *(uint4v*)&S.Bsh[nb][sf][sh2*16]   = b0;
            *(uint4v*)&S.Bsh[nb][sf][sh2*16+8] = b1;
            *(uint4v*)&S.Bsl[nb][sf][sh2*16]   = b2;
            *(uint4v*)&S.Bsl[nb][sf][sh2*16+8] = b3;
        }
    }
    float rv[4];
    #pragma unroll
    for (int j2 = 0; j2 < 4; ++j2) rv[j2] = rm[b*F + wc*64 + j2*16 + r16];
    __syncthreads();
    #pragma unroll
    for (int i = 0; i < 2; ++i)
        #pragma unroll
        for (int j2 = 0; j2 < 4; ++j2)
            #pragma unroll
            for (int reg = 0; reg < 4; ++reg)
                T[wr*32 + i*16 + kg*4 + reg][wc*64 + j2*16 + r16]
                    = acc[i][j2][reg] + rv[j2];
    __syncthreads();

    if (doLN) {
        int r = tid >> 2, q = tid & 3;
        float v[32];
        #pragma unroll
        for (int i = 0; i < 32; i += 4)
            *(float4*)&v[i] = *(const float4*)&T[r][q*32 + i];
        float s = 0.f;
        #pragma unroll
        for (int i = 0; i < 32; ++i) s += v[i];
        s += __shfl_xor(s, 1); s += __shfl_xor(s, 2);
        float mu = s * (1.0f/128.0f);
        float dv = 0.f;
        #pragma unroll
        for (int i = 0; i < 32; ++i) { float d = v[i] - mu; dv = fmaf(d, d, dv); }
        dv += __shfl_xor(dv, 1); dv += __shfl_xor(dv, 2);
        float rs = rsqrtf(dv * (1.0f/128.0f) + EPS);

        short hb[32], lb[32];
        {
            const short* rh = Vbh + ((size_t)b*T2 + t0 + r)*F + q*32;
            const short* rl = Vbl + ((size_t)b*T2 + t0 + r)*F + q*32;
            #pragma unroll
            for (int i = 0; i < 32; i += 8) {
                *(uint4v*)&hb[i] = *(const uint4v*)(rh + i);
                *(uint4v*)&lb[i] = *(const uint4v*)(rl + i);
            }
        }
        float gv[32], bv2[32];
        #pragma unroll
        for (int i = 0; i < 32; i += 4) {
            *(float4*)&gv[i]  = *(const float4*)&glj[q*32 + i];
            *(float4*)&bv2[i] = *(const float4*)&blj[q*32 + i];
        }
        unsigned ph[16], pl[16];
        #pragma unroll
        for (int i = 0; i < 32; i += 2) {
            float res0 = bf2f((unsigned short)hb[i])   + bf2f((unsigned short)lb[i]);
            float res1 = bf2f((unsigned short)hb[i+1]) + bf2f((unsigned short)lb[i+1]);
            float o0 = (v[i]   - mu)*rs*gv[i]   + bv2[i]   + res0;
            float o1 = (v[i+1] - mu)*rs*gv[i+1] + bv2[i+1] + res1;
            T[r][q*32+i] = o0; T[r][q*32+i+1] = o1;
            pack_hl(o0, o1, ph[i>>1], pl[i>>1]);
        }
        size_t ob = ((size_t)b*T2 + t0 + r)*F + q*32;
        store16u(&Vbh[ob], ph);
        store16u(&Vbl[ob], pl);
        __syncthreads();
    }
    {
        int f2 = tid >> 1, half = tid & 1;
        float sacc = 0.f;
        unsigned ph[16], pl[16];
        #pragma unroll
        for (int i = 0; i < 32; i += 2) {
            float v0 = T[half*32 + i][f2];
            float v1 = T[half*32 + i + 1][f2];
            sacc += v0 + v1;
            pack_hl(v0, v1, ph[i>>1], pl[i>>1]);
        }
        size_t ob = ((size_t)b*F + f2)*T2 + t0 + half*32;
        store16u(&OTh[ob], ph);
        store16u(&OTl[ob], pl);
        if (doLN)
            spartN[((size_t)b*100 + tblk*2 + half)*128 + f2] = sacc;
    }
}

// ------------- out = DXDY * W2(bf16) @ U(bf16 h/l), MFMA ------------------
__global__ __launch_bounds__(256) void k_gemm_out_mfma(
    const short* __restrict__ W2h,
    const short* __restrict__ Uth, const short* __restrict__ Utl,
    float* __restrict__ out)
{
    int id = blockIdx.x;
    int qb = id >> 3;
    if (qb >= 25) return;
    int job = (id & 7) * 25 + qb;
    int nt = job >> 3, b = job & 7;
    int n0 = nt * 64;

    __shared__ __align__(16) short As[2][64][40];
    __shared__ __align__(16) short Bh_s[2][128][40], Bl_s[2][128][40];

    int tid = threadIdx.x;
    int lane = tid & 63, wid = tid >> 6;
    int wr = wid >> 1, wc = wid & 1;
    int r16 = lane & 15, kg = lane >> 4;
    int srow = tid >> 2, sq2 = tid & 3;
    int sf = tid >> 1, sh2 = tid & 1;

    const short* ap  = W2h + (size_t)(n0 + srow)*T2 + sq2*8;
    const short* bhp = Uth + ((size_t)b*F + sf)*T2 + sh2*16;
    const short* blp = Utl + ((size_t)b*F + sf)*T2 + sh2*16;

    f32x4 acc[2][4];
    #pragma unroll
    for (int i = 0; i < 2; ++i)
        #pragma unroll
        for (int j2 = 0; j2 < 4; ++j2)
            acc[i][j2] = (f32x4){0.f,0.f,0.f,0.f};

    {
        *(uint4v*)&As[0][srow][sq2*8]     = *(const uint4v*)ap;
        *(uint4v*)&Bh_s[0][sf][sh2*16]    = *(const uint4v*)bhp;
        *(uint4v*)&Bh_s[0][sf][sh2*16+8]  = *(const uint4v*)(bhp + 8);
        *(uint4v*)&Bl_s[0][sf][sh2*16]    = *(const uint4v*)blp;
        *(uint4v*)&Bl_s[0][sf][sh2*16+8]  = *(const uint4v*)(blp + 8);
    }
    for (int it = 0; it < 100; ++it) {
        int cur = it & 1;
        uint4v ra, b0, b1, b2, b3;
        if (it < 99) {
            int ko = (it + 1) * 32;
            ra = *(const uint4v*)(ap + ko);
            b0 = *(const uint4v*)(bhp + ko); b1 = *(const uint4v*)(bhp + ko + 8);
            b2 = *(const uint4v*)(blp + ko); b3 = *(const uint4v*)(blp + ko + 8);
        }
        __syncthreads();
        bf16x8 ah[2], bh[4], bl[4];
        #pragma unroll
        for (int i = 0; i < 2; ++i)
            ah[i] = *(const bf16x8*)&As[cur][wr*32 + i*16 + r16][kg*8];
        #pragma unroll
        for (int j2 = 0; j2 < 4; ++j2) {
            bh[j2] = *(const bf16x8*)&Bh_s[cur][wc*64 + j2*16 + r16][kg*8];
            bl[j2] = *(const bf16x8*)&Bl_s[cur][wc*64 + j2*16 + r16][kg*8];
        }
        #pragma unroll
        for (int i = 0; i < 2; ++i)
            #pragma unroll
            for (int j2 = 0; j2 < 4; ++j2) {
                acc[i][j2] = __builtin_amdgcn_mfma_f32_16x16x32_bf16(ah[i], bh[j2], acc[i][j2], 0,0,0);
                acc[i][j2] = __builtin_amdgcn_mfma_f32_16x16x32_bf16(ah[i], bl[j2], acc[i][j2], 0,0,0);
            }
        if (it < 99) {
            int nb = cur ^ 1;
            *(uint4v*)&As[nb][srow][sq2*8]    = ra;
            *(uint4v*)&Bh_s[nb][sf][sh2*16]   = b0;
            *(uint4v*)&Bh_s[nb][sf][sh2*16+8] = b1;
            *(uint4v*)&Bl_s[nb][sf][sh2*16]   = b2;
            *(uint4v*)&Bl_s[nb][sf][sh2*16+8] = b3;
        }
    }
    #pragma unroll
    for (int i = 0; i < 2; ++i)
        #pragma unroll
        for (int j2 = 0; j2 < 4; ++j2)
            #pragma unroll
            for (int reg = 0; reg < 4; ++reg) {
                int n_out = n0 + wr*32 + i*16 + kg*4 + reg;
                int f_out = wc*64 + j2*16 + r16;
                out[((size_t)b*NT + n_out)*F + f_out] = DXDY * acc[i][j2][reg];
            }
}

// --------------------------------------------------------------- launcher
extern "C" void kernel_launch(void* const* d_in, const int* in_sizes, int n_in,
                              void* d_out, int out_size, void* d_ws, size_t ws_size,
                              hipStream_t stream)
{
    const float* xy  = (const float*)d_in[0];
    const float* kW1 = (const float*)d_in[1];
    const float* kb1 = (const float*)d_in[2];
    const float* kW2 = (const float*)d_in[3];
    const float* kb2 = (const float*)d_in[4];
    const float* kW3 = (const float*)d_in[5];
    const float* kb3 = (const float*)d_in[6];
    const float* fW1 = (const float*)d_in[7];
    const float* fb1 = (const float*)d_in[8];
    const float* fW2 = (const float*)d_in[9];
    const float* fb2 = (const float*)d_in[10];
    const float* fW3 = (const float*)d_in[11];
    const float* fb3 = (const float*)d_in[12];
    const float* Wq  = (const float*)d_in[13];
    const float* bq  = (const float*)d_in[14];
    const float* Wk  = (const float*)d_in[15];
    const float* bk  = (const float*)d_in[16];
    const float* g0  = (const float*)d_in[17];
    const float* b0  = (const float*)d_in[18];
    const float* gl  = (const float*)d_in[19];
    const float* bl  = (const float*)d_in[20];
    float* out = (float*)d_out;

    // ---- workspace carve (all sizes multiples of 8 elems -> 16B aligned)
    short* W2h  = (short*)d_ws;                 // 5,120,000
    short* Vbh  = W2h  + 5120000;               // 3,276,800
    short* Vbl  = Vbh  + 3276800;
    short* Vbth = Vbl  + 3276800;
    short* Vbtl = Vbth + 3276800;
    short* xyTh = Vbtl + 3276800;               // 1,638,400
    short* xyTl = xyTh + 1638400;
    short* Uth  = xyTl + 1638400;               // 3,276,800
    short* Utl  = Uth  + 3276800;
    short* Pnh  = Utl  + 3276800;               // 65,536
    short* Pnl  = Pnh  + 65536;
    short* Mth  = Pnl  + 65536;                 // 131,072
    short* Mtl  = Mth  + 131072;
    short* Gbh  = Mtl  + 131072;                // 131,072
    short* Gbl  = Gbh  + 131072;
    short* AhF  = Gbl  + 131072;                // 4,096
    short* AlF  = AhF  + 4096;
    float* Gpart  = (float*)(AlF + 4096);       // 3,276,800 f
    float* uB     = Gpart + 3276800;            // 512
    float* wB     = uB + 512;                   // 512
    float* cB     = wB + 512;                   // 4
    float* lnpart = cB + 4;                     // 400
    float* lnstats= lnpart + 400;               // 16
    float* rpart  = lnstats + 16;               // 1024
    float* rm     = rpart + 1024;               // 1024
    float* spartV = rm + 1024;                  // 102,400
    float* s2part = spartV + 102400;            // 51,200
    float* uvT    = s2part + 51200;             // 204,800

    k_prep_frag<<<1, 512, 0, stream>>>(kW2, fW2, AhF, AlF);
    k_prep_uv<<<dim3(200), 256, 0, stream>>>(kW1, kb1, fW1, fb1, uvT);
    k_mlp_mfma<<<dim3(MLPGRID), 256, 0, stream>>>(uvT, kb2, kW3, kb3,
                                                  fb2, fW3, fb3, AhF, AlF, W2h);
    k_precompute_P<<<dim3(4,9), 256, 0, stream>>>(Wq, bq, Wk, bk, Pnh, Pnl, uB, wB, cB);
    k_ln0_part<<<dim3(8,25), 256, 0, stream>>>(xy, lnpart);
    k_ln0_stats<<<1, 64, 0, stream>>>(lnpart, lnstats);
    k_ln0_apply<<<dim3(25,8), 256, 0, stream>>>(xy, g0, b0, lnstats,
                                                Vbh, Vbl, Vbth, Vbtl, spartV);
    k_prep_xyt<<<dim3(25,8), 256, 0, stream>>>(xy, xyTh, xyTl, s2part);

    for (int j = 0; j < 4; ++j) {
        if (j < 3)
            k_gemm_g_sym<<<dim3(25,8), 256, 0, stream>>>(Vbth, Vbtl, Gpart);
        else
            k_gemm_g_asym<<<dim3(25,8), 256, 0, stream>>>(xyTh, xyTl, Vbth, Vbtl, Gpart);
        k_gred<<<dim3(8,8), 256, 0, stream>>>(Gpart, wB + j*128, Gbh, Gbl, rpart);
        k_computeM<<<dim3(2,8), 256, 0, stream>>>(
            Gbh, Gbl,
            (j < 3) ? spartV : s2part, (j < 3) ? 100 : 50,
            Pnh + (size_t)j*16384, Pnl + (size_t)j*16384,
            uB + j*128, cB + j, rpart, Mth, Mtl, rm);
        if (j < 3)
            k_mid<<<dim3(50,8), 256, 0, stream>>>(Vbh, Vbl, Mth, Mtl, rm,
                                                  gl + j*128, bl + j*128, 1,
                                                  Vbth, Vbtl, spartV);
        else
            k_mid<<<dim3(50,8), 256, 0, stream>>>(Vbh, Vbl, Mth, Mtl, rm,
                                                  gl, bl, 0,
                                                  Uth, Utl, spartV);
    }

    k_gemm_out_mfma<<<dim3(256), 256, 0, stream>>>(W2h, Uth, Utl, out);
}